// Round 4
// baseline (877.146 us; speedup 1.0000x reference)
//
#include <hip/hip_runtime.h>
#include <cstddef>
#include <cstring>

#define HW 16384
#define CC 128
#define NB 8
#define GB 4   // batches per group

typedef short bf16x8_t __attribute__((ext_vector_type(8)));
typedef float floatx4 __attribute__((ext_vector_type(4)));

__device__ inline unsigned short f2bf(float f) {
  unsigned u; __builtin_memcpy(&u, &f, 4);
  u += 0x7fffu + ((u >> 16) & 1u);
  return (unsigned short)(u >> 16);
}
__device__ inline float bf2f(unsigned short s) {
  unsigned u = ((unsigned)s) << 16; float f; __builtin_memcpy(&f, &u, 4);
  return f;
}

// ---------------- one-time weight prep: (W*g) -> hi/lo bf16; lw -> bf16 -----
__global__ __launch_bounds__(256) void k_prep_w(
    const float* __restrict__ qw1, const float* __restrict__ kw1,
    const float* __restrict__ vw1, const float* __restrict__ qw2,
    const float* __restrict__ kw2, const float* __restrict__ vw2,
    const float* __restrict__ g1, const float* __restrict__ g2,
    const float* __restrict__ lw,
    unsigned short* __restrict__ Wsplit, unsigned short* __restrict__ lwbf) {
  const int t = threadIdx.x;
  const int m = blockIdx.y;
  if (m < 6) {
    const float* W = (m == 0) ? qw1 : (m == 1) ? kw1 : (m == 2) ? vw1
                   : (m == 3) ? qw2 : (m == 4) ? kw2 : vw2;
    const float* g = (m < 3) ? g1 : g2;
    const int idx = blockIdx.x * 256 + t;     // 0..2047
    const int o = idx >> 4;
    const int c0 = (idx & 15) * 8;
    unsigned short* hi = Wsplit + m * 32768 + o * 128 + c0;
    unsigned short* lo = hi + 16384;
#pragma unroll
    for (int j = 0; j < 8; ++j) {
      float v = W[o * 128 + c0 + j] * g[c0 + j];
      unsigned short h = f2bf(v);
      hi[j] = h;
      lo[j] = f2bf(v - bf2f(h));
    }
  } else {
    const int idx = blockIdx.x * 256 + t;     // 0..2047 (x16 elems = 32768)
#pragma unroll
    for (int j = 0; j < 16; ++j)
      lwbf[idx * 16 + j] = f2bf(lw[idx * 16 + j]);
  }
}

// ---------------- LayerNorm stats (mean / rstd per (b,p)), all 8 batches ----
// float2-vectorized: 2 pixels per thread, same per-element FP order.
__global__ __launch_bounds__(256) void k_ln_stats(const float* __restrict__ x,
                                                  float* __restrict__ mean,
                                                  float* __restrict__ rstd) {
  int idx = blockIdx.x * 256 + threadIdx.x;   // 0 .. 65535
  int p2 = idx * 2;
  int b = p2 >> 14;
  int p = p2 & (HW - 1);
  const float* xp = x + ((size_t)b << 21) + p;
  float s0 = 0.f, ss0 = 0.f, s1 = 0.f, ss1 = 0.f;
  for (int c = 0; c < CC; ++c) {
    float2 v = *reinterpret_cast<const float2*>(xp + ((size_t)c << 14));
    s0 += v.x; ss0 += v.x * v.x;
    s1 += v.y; ss1 += v.y * v.y;
  }
  float m0 = s0 * (1.0f / CC), m1 = s1 * (1.0f / CC);
  float var0 = ss0 * (1.0f / CC) - m0 * m0;
  float var1 = ss1 * (1.0f / CC) - m1 * m1;
  *reinterpret_cast<float2*>(mean + p2) = (float2){m0, m1};
  *reinterpret_cast<float2*>(rstd + p2) =
      (float2){rsqrtf(var0 + 1e-5f), rsqrtf(var1 + 1e-5f)};
}

// ---------------- split-bf16 MFMA LN+1x1 conv, pre-split weights ------------
// (round-2 proven version: staged X, LDS B operand, A from L2-hot Whi/Wlo)
__global__ __launch_bounds__(256) void k_conv1x1_mfma(
    const float* __restrict__ X,
    const unsigned short* __restrict__ Whi, const unsigned short* __restrict__ Wlo,
    const float* __restrict__ bias,
    const float* __restrict__ mean, const float* __restrict__ rstd,
    float* __restrict__ Y, int b0) {
  __shared__ __align__(16) float raw[32][132];   // X chunk [c][p]
  __shared__ __align__(16) short Bh[128][40];    // Xn hi [p][c_local]
  __shared__ __align__(16) short Bl[128][40];
  const int bl = blockIdx.y;
  const int b = b0 + bl;
  const int p0 = blockIdx.x * 128;
  const int t = threadIdx.x;
  const int lane = t & 63, wv = t >> 6;
  const int quad = lane >> 4, l15 = lane & 15;
  const int wr = wv >> 1, wc = wv & 1;

  const int s1c = t >> 3, s1p = (t & 7) * 16;
  const int s2p = t & 127, s2o = t >> 7;
  const float mu = mean[b * HW + p0 + s2p];
  const float rs = rstd[b * HW + p0 + s2p];

  const float* Xb = X + ((size_t)b << 21);
  floatx4 acc[4][4];
#pragma unroll
  for (int i = 0; i < 4; ++i)
#pragma unroll
    for (int j = 0; j < 4; ++j) acc[i][j] = (floatx4){0.f, 0.f, 0.f, 0.f};

  for (int k0 = 0; k0 < 128; k0 += 32) {
    {
      const float* xp = Xb + ((size_t)(k0 + s1c) << 14) + p0 + s1p;
#pragma unroll
      for (int u = 0; u < 4; ++u)
        *reinterpret_cast<float4*>(&raw[s1c][s1p + 4 * u]) =
            *reinterpret_cast<const float4*>(xp + 4 * u);
    }
    __syncthreads();
#pragma unroll
    for (int item = 0; item < 2; ++item) {
      const int oct = s2o + 2 * item;     // 0..3
      short th[8], tl[8];
#pragma unroll
      for (int jj = 0; jj < 8; ++jj) {
        float v = (raw[oct * 8 + jj][s2p] - mu) * rs;
        unsigned short h = f2bf(v);
        th[jj] = (short)h;
        tl[jj] = (short)f2bf(v - bf2f(h));
      }
      *reinterpret_cast<bf16x8_t*>(&Bh[s2p][oct * 8]) =
          *reinterpret_cast<bf16x8_t*>(&th[0]);
      *reinterpret_cast<bf16x8_t*>(&Bl[s2p][oct * 8]) =
          *reinterpret_cast<bf16x8_t*>(&tl[0]);
    }
    __syncthreads();
    bf16x8_t afh[4], afl[4], bfh[4], bfl[4];
#pragma unroll
    for (int i = 0; i < 4; ++i) {
      const int m = wr * 64 + i * 16 + l15;
      afh[i] = *reinterpret_cast<const bf16x8_t*>(Whi + m * 128 + k0 + quad * 8);
      afl[i] = *reinterpret_cast<const bf16x8_t*>(Wlo + m * 128 + k0 + quad * 8);
    }
#pragma unroll
    for (int j = 0; j < 4; ++j) {
      const int p = wc * 64 + j * 16 + l15;
      bfh[j] = *reinterpret_cast<const bf16x8_t*>(&Bh[p][quad * 8]);
      bfl[j] = *reinterpret_cast<const bf16x8_t*>(&Bl[p][quad * 8]);
    }
#pragma unroll
    for (int i = 0; i < 4; ++i)
#pragma unroll
      for (int j = 0; j < 4; ++j) {
        acc[i][j] = __builtin_amdgcn_mfma_f32_16x16x32_bf16(afh[i], bfh[j], acc[i][j], 0, 0, 0);
        acc[i][j] = __builtin_amdgcn_mfma_f32_16x16x32_bf16(afh[i], bfl[j], acc[i][j], 0, 0, 0);
        acc[i][j] = __builtin_amdgcn_mfma_f32_16x16x32_bf16(afl[i], bfh[j], acc[i][j], 0, 0, 0);
      }
    __syncthreads();
  }
  float* Yb = Y + ((size_t)bl << 21);
#pragma unroll
  for (int i = 0; i < 4; ++i) {
#pragma unroll
    for (int j = 0; j < 4; ++j) {
#pragma unroll
      for (int r = 0; r < 4; ++r) {
        const int o = wr * 64 + i * 16 + quad * 4 + r;
        const int p = p0 + wc * 64 + j * 16 + l15;
        Yb[((size_t)o << 14) + p] = acc[i][j][r] + bias[o];
      }
    }
  }
}

// ---------------- split-bf16 MFMA score GEMM with fused depthwise 3x3 --------
// c-dimension split across blockIdx.z (2 halves): each block computes a
// 64x128 (c,d) half-tile. Q-side dw/transpose halves; K-side duplicated.
// LDS 47.6KB -> 3 blocks/CU; grid 128 x GB x 2 = 1024 blocks.
// Per-output FP order bitwise-identical to the unsplit version.
__global__ __launch_bounds__(256) void k_score_mfma(
    const float* __restrict__ Yq, const float* __restrict__ Yk,
    const float* __restrict__ qdw, const float* __restrict__ qdb,
    const float* __restrict__ kdw, const float* __restrict__ kdb,
    float* __restrict__ P) {
  __shared__ __align__(16) float raw[32][132];   // dw out chunk [h][w]
  __shared__ __align__(16) short Ah[64][40];     // Q side [w-local][h] hi
  __shared__ __align__(16) short Al[64][40];
  __shared__ __align__(16) short Bh[128][40];    // K side [w][h] hi
  __shared__ __align__(16) short Bl[128][40];
  const int ch = blockIdx.x;
  const int bl = blockIdx.y;
  const int chalf = blockIdx.z;
  const int t = threadIdx.x;
  const int lane = t & 63, wv = t >> 6;
  const int quad = lane >> 4, l15 = lane & 15;
  const int wr = wv >> 1, wc = wv & 1;
  const int h_loc = t >> 3;
  const int w0 = (t & 7) * 16;               // K-side staging cols
  const int wlq = (t & 7) * 8;               // Q-side local col
  const int w0q = wlq + chalf * 64;          // Q-side global col
  const int s2w = t & 127, s2o = t >> 7;     // K transpose
  const int qtw = t & 63, qto = t >> 6;      // Q transpose
  const float* Yqb = Yq + ((size_t)bl << 21) + ((size_t)ch << 14);
  const float* Ykb = Yk + ((size_t)bl << 21) + ((size_t)ch << 14);
  const float* qwt = qdw + ch * 9;
  const float* kwt = kdw + ch * 9;
  const float qbv = qdb[ch], kbv = kdb[ch];

  floatx4 acc[2][4];
#pragma unroll
  for (int i = 0; i < 2; ++i)
#pragma unroll
    for (int j = 0; j < 4; ++j) acc[i][j] = (floatx4){0.f, 0.f, 0.f, 0.f};

  for (int k0 = 0; k0 < 128; k0 += 32) {
    const int h = k0 + h_loc;
    // ---- Q side: dw 3x3 on 8 cols at w0q ----
    {
      float a[8];
#pragma unroll
      for (int j = 0; j < 8; ++j) a[j] = qbv;
#pragma unroll
      for (int dy = 0; dy < 3; ++dy) {
        const int hh = h + dy - 1;
        if (hh < 0 || hh > 127) continue;
        const float* rp = Yqb + (hh << 7) + w0q;
        float4 f0 = *reinterpret_cast<const float4*>(rp);
        float4 f1 = *reinterpret_cast<const float4*>(rp + 4);
        float s[10];
        s[1] = f0.x; s[2] = f0.y; s[3] = f0.z; s[4] = f0.w;
        s[5] = f1.x; s[6] = f1.y; s[7] = f1.z; s[8] = f1.w;
        s[0] = (w0q > 0) ? rp[-1] : 0.f;
        s[9] = (w0q < 120) ? rp[8] : 0.f;
        const float wa = qwt[dy * 3 + 0], wb = qwt[dy * 3 + 1], wc2 = qwt[dy * 3 + 2];
#pragma unroll
        for (int j = 0; j < 8; ++j)
          a[j] = fmaf(s[j], wa, fmaf(s[j + 1], wb, fmaf(s[j + 2], wc2, a[j])));
      }
      *reinterpret_cast<float4*>(&raw[h_loc][wlq]) =
          (float4){a[0], a[1], a[2], a[3]};
      *reinterpret_cast<float4*>(&raw[h_loc][wlq + 4]) =
          (float4){a[4], a[5], a[6], a[7]};
    }
    __syncthreads();
    {
      // transpose [h][w-local] -> Ah/Al[w-local][h] + hi/lo split
      short th[8], tl[8];
#pragma unroll
      for (int jj = 0; jj < 8; ++jj) {
        float v = raw[qto * 8 + jj][qtw];
        unsigned short hb = f2bf(v);
        th[jj] = (short)hb;
        tl[jj] = (short)f2bf(v - bf2f(hb));
      }
      *reinterpret_cast<bf16x8_t*>(&Ah[qtw][qto * 8]) =
          *reinterpret_cast<bf16x8_t*>(&th[0]);
      *reinterpret_cast<bf16x8_t*>(&Al[qtw][qto * 8]) =
          *reinterpret_cast<bf16x8_t*>(&tl[0]);
    }
    __syncthreads();
    // ---- K side: dw 3x3 on 16 cols at w0 (full 128) ----
    {
      float a[16];
#pragma unroll
      for (int j = 0; j < 16; ++j) a[j] = kbv;
#pragma unroll
      for (int dy = 0; dy < 3; ++dy) {
        const int hh = h + dy - 1;
        if (hh < 0 || hh > 127) continue;
        const float* rp = Ykb + (hh << 7) + w0;
        float4 f0 = *reinterpret_cast<const float4*>(rp);
        float4 f1 = *reinterpret_cast<const float4*>(rp + 4);
        float4 f2 = *reinterpret_cast<const float4*>(rp + 8);
        float4 f3 = *reinterpret_cast<const float4*>(rp + 12);
        float s[18];
        s[1] = f0.x;  s[2] = f0.y;  s[3] = f0.z;  s[4] = f0.w;
        s[5] = f1.x;  s[6] = f1.y;  s[7] = f1.z;  s[8] = f1.w;
        s[9] = f2.x;  s[10] = f2.y; s[11] = f2.z; s[12] = f2.w;
        s[13] = f3.x; s[14] = f3.y; s[15] = f3.z; s[16] = f3.w;
        s[0] = (w0 > 0) ? rp[-1] : 0.f;
        s[17] = (w0 < 112) ? rp[16] : 0.f;
        const float wa = kwt[dy * 3 + 0], wb = kwt[dy * 3 + 1], wc2 = kwt[dy * 3 + 2];
#pragma unroll
        for (int j = 0; j < 16; ++j)
          a[j] = fmaf(s[j], wa, fmaf(s[j + 1], wb, fmaf(s[j + 2], wc2, a[j])));
      }
#pragma unroll
      for (int u = 0; u < 4; ++u)
        *reinterpret_cast<float4*>(&raw[h_loc][w0 + 4 * u]) =
            (float4){a[4 * u], a[4 * u + 1], a[4 * u + 2], a[4 * u + 3]};
    }
    __syncthreads();
    {
#pragma unroll
      for (int item = 0; item < 2; ++item) {
        const int oct = s2o + 2 * item;   // 0..3
        short th[8], tl[8];
#pragma unroll
        for (int jj = 0; jj < 8; ++jj) {
          float v = raw[oct * 8 + jj][s2w];
          unsigned short hb = f2bf(v);
          th[jj] = (short)hb;
          tl[jj] = (short)f2bf(v - bf2f(hb));
        }
        *reinterpret_cast<bf16x8_t*>(&Bh[s2w][oct * 8]) =
            *reinterpret_cast<bf16x8_t*>(&th[0]);
        *reinterpret_cast<bf16x8_t*>(&Bl[s2w][oct * 8]) =
            *reinterpret_cast<bf16x8_t*>(&tl[0]);
      }
    }
    __syncthreads();
    // ---- MFMA, 3 split passes ----
    bf16x8_t afh[2], afl[2], bfh[4], bfl[4];
#pragma unroll
    for (int i = 0; i < 2; ++i) {
      const int m = wr * 32 + i * 16 + l15;
      afh[i] = *reinterpret_cast<const bf16x8_t*>(&Ah[m][quad * 8]);
      afl[i] = *reinterpret_cast<const bf16x8_t*>(&Al[m][quad * 8]);
    }
#pragma unroll
    for (int j = 0; j < 4; ++j) {
      const int n = wc * 64 + j * 16 + l15;
      bfh[j] = *reinterpret_cast<const bf16x8_t*>(&Bh[n][quad * 8]);
      bfl[j] = *reinterpret_cast<const bf16x8_t*>(&Bl[n][quad * 8]);
    }
#pragma unroll
    for (int i = 0; i < 2; ++i)
#pragma unroll
      for (int j = 0; j < 4; ++j) {
        acc[i][j] = __builtin_amdgcn_mfma_f32_16x16x32_bf16(afh[i], bfh[j], acc[i][j], 0, 0, 0);
        acc[i][j] = __builtin_amdgcn_mfma_f32_16x16x32_bf16(afh[i], bfl[j], acc[i][j], 0, 0, 0);
        acc[i][j] = __builtin_amdgcn_mfma_f32_16x16x32_bf16(afl[i], bfh[j], acc[i][j], 0, 0, 0);
      }
  }
  float* Pp = P + ((size_t)(ch * GB + bl) << 14);
#pragma unroll
  for (int i = 0; i < 2; ++i) {
#pragma unroll
    for (int j = 0; j < 4; ++j) {
#pragma unroll
      for (int r = 0; r < 4; ++r) {
        const int c = chalf * 64 + wr * 32 + i * 16 + quad * 4 + r;
        const int d = wc * 64 + j * 16 + l15;
        Pp[c * 128 + d] = acc[i][j][r];
      }
    }
  }
}

// ---------------- fused: split-K reduce (128 partials) + softmax -> bf16 ----
__global__ __launch_bounds__(128) void k_reduce_softmax(
    const float* __restrict__ P, unsigned short* __restrict__ Sbf) {
  __shared__ float red[128];
  const int row = blockIdx.x;            // bl*128 + c
  const int bl = row >> 7, c = row & 127;
  const int t = threadIdx.x;
  const size_t rem = ((size_t)c << 7) + t;
  float v = 0.f;
  for (int ch = 0; ch < 128; ++ch)
    v += P[((size_t)(ch * GB + bl) << 14) + rem];
  red[t] = v;
  __syncthreads();
  for (int s = 64; s > 0; s >>= 1) {
    if (t < s) red[t] = fmaxf(red[t], red[t + s]);
    __syncthreads();
  }
  float mx = red[0];
  __syncthreads();
  float e = expf(v - mx);
  red[t] = e;
  __syncthreads();
  for (int s = 64; s > 0; s >>= 1) {
    if (t < s) red[t] += red[t + s];
    __syncthreads();
  }
  Sbf[((size_t)bl << 14) + rem] = f2bf(e / red[0]);
}

// ---------------- depthwise 3x3 + transpose: Vt[p][c] bf16 -----------------
__global__ __launch_bounds__(256) void k_dw_t(const float* __restrict__ Y,
                                              const float* __restrict__ Kw,
                                              const float* __restrict__ db,
                                              unsigned short* __restrict__ Vt) {
  __shared__ unsigned short T[128][33];
  const int h = blockIdx.x;
  const int c0 = blockIdx.y * 32;
  const int bl = blockIdx.z;
  const int t = threadIdx.x;
  const int cl = t >> 3;
  const int w0 = (t & 7) * 16;
  const int c = c0 + cl;
  const float* Yc = Y + ((size_t)bl << 21) + ((size_t)c << 14);
  const float* wt = Kw + c * 9;
  float a[16];
#pragma unroll
  for (int j = 0; j < 16; ++j) a[j] = db[c];
#pragma unroll
  for (int dy = 0; dy < 3; ++dy) {
    const int hh = h + dy - 1;
    if (hh < 0 || hh > 127) continue;
    const float* rp = Yc + (hh << 7) + w0;
    float4 f0 = *reinterpret_cast<const float4*>(rp);
    float4 f1 = *reinterpret_cast<const float4*>(rp + 4);
    float4 f2 = *reinterpret_cast<const float4*>(rp + 8);
    float4 f3 = *reinterpret_cast<const float4*>(rp + 12);
    float s[18];
    s[1] = f0.x;  s[2] = f0.y;  s[3] = f0.z;  s[4] = f0.w;
    s[5] = f1.x;  s[6] = f1.y;  s[7] = f1.z;  s[8] = f1.w;
    s[9] = f2.x;  s[10] = f2.y; s[11] = f2.z; s[12] = f2.w;
    s[13] = f3.x; s[14] = f3.y; s[15] = f3.z; s[16] = f3.w;
    s[0] = (w0 > 0) ? rp[-1] : 0.f;
    s[17] = (w0 < 112) ? rp[16] : 0.f;
    const float wa = wt[dy * 3 + 0], wb = wt[dy * 3 + 1], wc2 = wt[dy * 3 + 2];
#pragma unroll
    for (int j = 0; j < 16; ++j)
      a[j] = fmaf(s[j], wa, fmaf(s[j + 1], wb, fmaf(s[j + 2], wc2, a[j])));
  }
#pragma unroll
  for (int j = 0; j < 16; ++j) T[w0 + j][cl] = f2bf(a[j]);
  __syncthreads();
  const int w = t >> 1, half = t & 1;
  unsigned short tmp[16];
#pragma unroll
  for (int j = 0; j < 16; ++j) tmp[j] = T[w][half * 16 + j];
  uint4 v0, v1;
  unsigned* vp0 = reinterpret_cast<unsigned*>(&v0);
  unsigned* vp1 = reinterpret_cast<unsigned*>(&v1);
#pragma unroll
  for (int j = 0; j < 4; ++j) {
    vp0[j] = (unsigned)tmp[2 * j] | ((unsigned)tmp[2 * j + 1] << 16);
    vp1[j] = (unsigned)tmp[8 + 2 * j] | ((unsigned)tmp[8 + 2 * j + 1] << 16);
  }
  unsigned short* dst = Vt + ((size_t)bl << 21) + ((size_t)((h << 7) + w) << 7)
                        + c0 + half * 16;
  *reinterpret_cast<uint4*>(dst) = v0;
  *reinterpret_cast<uint4*>(dst + 8) = v1;
}

// ---------------- MFMA: O[c,p] = sum_d Att[c,d] * V[d,p] — LDS-free --------
__global__ __launch_bounds__(256) void k_av_mfma(
    const unsigned short* __restrict__ Sbf, const unsigned short* __restrict__ Vt,
    unsigned short* __restrict__ O) {
  const int bl = blockIdx.y;
  const int p0 = blockIdx.x * 128;
  const int t = threadIdx.x;
  const int lane = t & 63, wv = t >> 6;
  const int quad = lane >> 4, l15 = lane & 15;
  const int wr = wv >> 1, wc = wv & 1;
  const unsigned short* Sb = Sbf + ((size_t)bl << 14);
  floatx4 acc[4][4];
#pragma unroll
  for (int i = 0; i < 4; ++i)
#pragma unroll
    for (int j = 0; j < 4; ++j) acc[i][j] = (floatx4){0.f, 0.f, 0.f, 0.f};
  const unsigned short* Vb = Vt + ((size_t)bl << 21);
#pragma unroll
  for (int d0 = 0; d0 < 128; d0 += 32) {
    bf16x8_t af[4], bf[4];
#pragma unroll
    for (int i = 0; i < 4; ++i) {
      const int m = wr * 64 + i * 16 + l15;
      af[i] = *reinterpret_cast<const bf16x8_t*>(Sb + m * 128 + d0 + quad * 8);
    }
#pragma unroll
    for (int j = 0; j < 4; ++j) {
      const int p = p0 + wc * 64 + j * 16 + l15;
      bf[j] = *reinterpret_cast<const bf16x8_t*>(Vb + ((size_t)p << 7) + d0 + quad * 8);
    }
#pragma unroll
    for (int i = 0; i < 4; ++i)
#pragma unroll
      for (int j = 0; j < 4; ++j)
        acc[i][j] = __builtin_amdgcn_mfma_f32_16x16x32_bf16(af[i], bf[j], acc[i][j], 0, 0, 0);
  }
  unsigned short* Ob = O + ((size_t)bl << 21);
#pragma unroll
  for (int i = 0; i < 4; ++i) {
#pragma unroll
    for (int j = 0; j < 4; ++j) {
#pragma unroll
      for (int r = 0; r < 4; ++r) {
        const int c = wr * 64 + i * 16 + quad * 4 + r;
        const int p = p0 + wc * 64 + j * 16 + l15;
        Ob[((size_t)c << 14) + p] = f2bf(acc[i][j][r]);
      }
    }
  }
}

// ---------------- MFMA final: LDS-free, lw pre-converted to bf16 ------------
__global__ __launch_bounds__(256) void k_final2_mfma(
    const unsigned short* __restrict__ A1, const unsigned short* __restrict__ A2,
    const unsigned short* __restrict__ lwbf, const float* __restrict__ lb,
    const float* __restrict__ Fi, const float* __restrict__ Fw,
    float* __restrict__ out, int b0) {
  const int c2 = blockIdx.x;
  const int bl = blockIdx.y;
  const int b = b0 + bl;
  const int t = threadIdx.x;
  const int lane = t & 63, wv = t >> 6;
  const int quad = lane >> 4, l15 = lane & 15;
  const int wr = wv >> 1, wc = wv & 1;
  floatx4 acc[4][4];
#pragma unroll
  for (int i = 0; i < 4; ++i)
#pragma unroll
    for (int j = 0; j < 4; ++j) acc[i][j] = (floatx4){0.f, 0.f, 0.f, 0.f};
#pragma unroll
  for (int phase = 0; phase < 2; ++phase) {
    const unsigned short* Ub = (phase ? A2 : A1) + ((size_t)bl << 21) + c2 * 128;
#pragma unroll
    for (int d0 = 0; d0 < 128; d0 += 32) {
      bf16x8_t af[4], bf[4];
#pragma unroll
      for (int i = 0; i < 4; ++i) {
        const int m = wr * 64 + i * 16 + l15;
        af[i] = *reinterpret_cast<const bf16x8_t*>(
            lwbf + m * 256 + phase * 128 + d0 + quad * 8);
      }
#pragma unroll
      for (int j = 0; j < 4; ++j) {
        const int n = wc * 64 + j * 16 + l15;
        bf[j] = *reinterpret_cast<const bf16x8_t*>(Ub + ((size_t)n << 14) + d0 + quad * 8);
      }
#pragma unroll
      for (int i = 0; i < 4; ++i)
#pragma unroll
        for (int j = 0; j < 4; ++j)
          acc[i][j] = __builtin_amdgcn_mfma_f32_16x16x32_bf16(af[i], bf[j], acc[i][j], 0, 0, 0);
    }
  }
  const size_t obase = ((size_t)b << 21) + ((size_t)c2 << 14);
#pragma unroll
  for (int i = 0; i < 4; ++i) {
#pragma unroll
    for (int j = 0; j < 4; ++j) {
#pragma unroll
      for (int r = 0; r < 4; ++r) {
        const int h2 = wr * 64 + i * 16 + quad * 4 + r;
        const int w2 = wc * 64 + j * 16 + l15;
        const size_t a = obase + ((size_t)h2 << 7) + w2;
        out[a] = acc[i][j][r] + lb[h2] + Fi[a] + Fw[a];
      }
    }
  }
}

extern "C" void kernel_launch(void* const* d_in, const int* in_sizes, int n_in,
                              void* d_out, int out_size, void* d_ws, size_t ws_size,
                              hipStream_t stream) {
  const float* F_i  = (const float*)d_in[0];
  const float* F_w  = (const float*)d_in[1];
  const float* g1   = (const float*)d_in[2];
  const float* g2   = (const float*)d_in[3];
  const float* qw1  = (const float*)d_in[4];
  const float* kw1  = (const float*)d_in[5];
  const float* vw1  = (const float*)d_in[6];
  const float* qw2  = (const float*)d_in[7];
  const float* kw2  = (const float*)d_in[8];
  const float* vw2  = (const float*)d_in[9];
  const float* qb1  = (const float*)d_in[10];
  const float* kb1  = (const float*)d_in[11];
  const float* vb1  = (const float*)d_in[12];
  const float* qb2  = (const float*)d_in[13];
  const float* kb2  = (const float*)d_in[14];
  const float* vb2  = (const float*)d_in[15];
  const float* qdw1 = (const float*)d_in[16];
  const float* kdw1 = (const float*)d_in[17];
  const float* vdw1 = (const float*)d_in[18];
  const float* qdw2 = (const float*)d_in[19];
  const float* kdw2 = (const float*)d_in[20];
  const float* vdw2 = (const float*)d_in[21];
  const float* qdb1 = (const float*)d_in[22];
  const float* kdb1 = (const float*)d_in[23];
  const float* vdb1 = (const float*)d_in[24];
  const float* qdb2 = (const float*)d_in[25];
  const float* kdb2 = (const float*)d_in[26];
  const float* vdb2 = (const float*)d_in[27];
  const float* lw   = (const float*)d_in[28];
  const float* lb   = (const float*)d_in[29];
  float* out = (float*)d_out;

  // ---- workspace (~114.6 MiB peak; <=116 MiB proven safe) ----
  char* w = (char*)d_ws;
  const size_t NTOT = (size_t)NB * HW;                      // 131072
  float* meanI = (float*)w; w += NTOT * 4;
  float* rstdI = (float*)w; w += NTOT * 4;
  float* meanW = (float*)w; w += NTOT * 4;
  float* rstdW = (float*)w; w += NTOT * 4;
  unsigned short* Sbf = (unsigned short*)w; w += (size_t)GB * HW * 2;     // 128 KiB
  unsigned short* Wsplit = (unsigned short*)w; w += 6 * 32768 * 2;        // 384 KiB
  unsigned short* lwbf = (unsigned short*)w; w += 32768 * 2;              // 64 KiB
  float* P     = (float*)w; w += (size_t)128 * GB * HW * 4; // 32 MiB
  float* Yq    = (float*)w; w += ((size_t)GB << 21) * 4;    // 32 MiB
  char*  Ykreg = w;         w += ((size_t)GB << 21) * 4;    // 32 MiB (overlaid)
  float* Yk    = (float*)Ykreg;
  unsigned short* Vt = (unsigned short*)Ykreg;                            // 16 MiB
  unsigned short* A2 = (unsigned short*)(Ykreg + ((size_t)GB << 21) * 2); // 16 MiB
  unsigned short* A1 = (unsigned short*)w; w += ((size_t)GB << 21) * 2;   // 16 MiB

  // pre-split conv weights (W*g -> hi/lo bf16) and lw -> bf16
  const unsigned short* Wh0 = Wsplit + 0 * 32768;  // qw1*g1
  const unsigned short* Wh1 = Wsplit + 1 * 32768;  // kw1*g1
  const unsigned short* Wh2 = Wsplit + 2 * 32768;  // vw1*g1
  const unsigned short* Wh3 = Wsplit + 3 * 32768;  // qw2*g2
  const unsigned short* Wh4 = Wsplit + 4 * 32768;  // kw2*g2
  const unsigned short* Wh5 = Wsplit + 5 * 32768;  // vw2*g2

  dim3 blk(256);
  k_prep_w<<<dim3(8, 7), blk, 0, stream>>>(qw1, kw1, vw1, qw2, kw2, vw2,
                                           g1, g2, lw, Wsplit, lwbf);
  k_ln_stats<<<dim3(256), blk, 0, stream>>>(F_i, meanI, rstdI);
  k_ln_stats<<<dim3(256), blk, 0, stream>>>(F_w, meanW, rstdW);

  for (int b0 = 0; b0 < NB; b0 += GB) {
    // ---- attention 1: a1 = softmax(Qi^T Kw) ; Aw = a1 @ Vw -> A1 ----
    k_conv1x1_mfma<<<dim3(128, GB), blk, 0, stream>>>(F_i, Wh0, Wh0 + 16384, qb1, meanI, rstdI, Yq, b0);
    k_conv1x1_mfma<<<dim3(128, GB), blk, 0, stream>>>(F_w, Wh4, Wh4 + 16384, kb2, meanW, rstdW, Yk, b0);
    k_score_mfma<<<dim3(128, GB, 2), blk, 0, stream>>>(Yq, Yk, qdw1, qdb1, kdw2, kdb2, P);
    k_reduce_softmax<<<dim3(GB * 128), dim3(128), 0, stream>>>(P, Sbf);
    k_conv1x1_mfma<<<dim3(128, GB), blk, 0, stream>>>(F_w, Wh5, Wh5 + 16384, vb2, meanW, rstdW, Yq, b0);
    k_dw_t<<<dim3(128, 4, GB), blk, 0, stream>>>(Yq, vdw2, vdb2, Vt);
    k_av_mfma<<<dim3(128, GB), blk, 0, stream>>>(Sbf, Vt, A1);

    // ---- attention 2: a2 = softmax(Qw^T Ki) ; Ai = a2 @ Vi -> A2 ----
    k_conv1x1_mfma<<<dim3(128, GB), blk, 0, stream>>>(F_w, Wh3, Wh3 + 16384, qb2, meanW, rstdW, Yq, b0);
    k_conv1x1_mfma<<<dim3(128, GB), blk, 0, stream>>>(F_i, Wh1, Wh1 + 16384, kb1, meanI, rstdI, Yk, b0);
    k_score_mfma<<<dim3(128, GB, 2), blk, 0, stream>>>(Yq, Yk, qdw2, qdb2, kdw1, kdb1, P);
    k_reduce_softmax<<<dim3(GB * 128), dim3(128), 0, stream>>>(P, Sbf);
    k_conv1x1_mfma<<<dim3(128, GB), blk, 0, stream>>>(F_i, Wh2, Wh2 + 16384, vb1, meanI, rstdI, Yq, b0);
    k_dw_t<<<dim3(128, 4, GB), blk, 0, stream>>>(Yq, vdw1, vdb1, Vt);
    k_av_mfma<<<dim3(128, GB), blk, 0, stream>>>(Sbf, Vt, A2);

    // ---- fused final linear + residual (single out write) ----
    k_final2_mfma<<<dim3(128, GB), blk, 0, stream>>>(A1, A2, lwbf, lb, F_i, F_w, out, b0);
  }
}

// Round 5
// 862.445 us; speedup vs baseline: 1.0170x; 1.0170x over previous
//
#include <hip/hip_runtime.h>
#include <cstddef>
#include <cstring>

#define HW 16384
#define CC 128
#define NB 8
#define GB 4   // batches per group

typedef short bf16x8_t __attribute__((ext_vector_type(8)));
typedef float floatx4 __attribute__((ext_vector_type(4)));

__device__ inline unsigned short f2bf(float f) {
  unsigned u; __builtin_memcpy(&u, &f, 4);
  u += 0x7fffu + ((u >> 16) & 1u);
  return (unsigned short)(u >> 16);
}
__device__ inline float bf2f(unsigned short s) {
  unsigned u = ((unsigned)s) << 16; float f; __builtin_memcpy(&f, &u, 4);
  return f;
}

// ---------------- one-time weight prep: (W*g) -> hi/lo bf16; lw -> bf16 -----
__global__ __launch_bounds__(256) void k_prep_w(
    const float* __restrict__ qw1, const float* __restrict__ kw1,
    const float* __restrict__ vw1, const float* __restrict__ qw2,
    const float* __restrict__ kw2, const float* __restrict__ vw2,
    const float* __restrict__ g1, const float* __restrict__ g2,
    const float* __restrict__ lw,
    unsigned short* __restrict__ Wsplit, unsigned short* __restrict__ lwbf) {
  const int t = threadIdx.x;
  const int m = blockIdx.y;
  if (m < 6) {
    const float* W = (m == 0) ? qw1 : (m == 1) ? kw1 : (m == 2) ? vw1
                   : (m == 3) ? qw2 : (m == 4) ? kw2 : vw2;
    const float* g = (m < 3) ? g1 : g2;
    const int idx = blockIdx.x * 256 + t;     // 0..2047
    const int o = idx >> 4;
    const int c0 = (idx & 15) * 8;
    unsigned short* hi = Wsplit + m * 32768 + o * 128 + c0;
    unsigned short* lo = hi + 16384;
#pragma unroll
    for (int j = 0; j < 8; ++j) {
      float v = W[o * 128 + c0 + j] * g[c0 + j];
      unsigned short h = f2bf(v);
      hi[j] = h;
      lo[j] = f2bf(v - bf2f(h));
    }
  } else {
    const int idx = blockIdx.x * 256 + t;     // 0..2047 (x16 elems = 32768)
#pragma unroll
    for (int j = 0; j < 16; ++j)
      lwbf[idx * 16 + j] = f2bf(lw[idx * 16 + j]);
  }
}

// ---------------- LayerNorm stats (mean / rstd per (b,p)), all 8 batches ----
// float2-vectorized: 2 pixels per thread, same per-element FP order.
__global__ __launch_bounds__(256) void k_ln_stats(const float* __restrict__ x,
                                                  float* __restrict__ mean,
                                                  float* __restrict__ rstd) {
  int idx = blockIdx.x * 256 + threadIdx.x;   // 0 .. 65535
  int p2 = idx * 2;
  int b = p2 >> 14;
  int p = p2 & (HW - 1);
  const float* xp = x + ((size_t)b << 21) + p;
  float s0 = 0.f, ss0 = 0.f, s1 = 0.f, ss1 = 0.f;
  for (int c = 0; c < CC; ++c) {
    float2 v = *reinterpret_cast<const float2*>(xp + ((size_t)c << 14));
    s0 += v.x; ss0 += v.x * v.x;
    s1 += v.y; ss1 += v.y * v.y;
  }
  float m0 = s0 * (1.0f / CC), m1 = s1 * (1.0f / CC);
  float var0 = ss0 * (1.0f / CC) - m0 * m0;
  float var1 = ss1 * (1.0f / CC) - m1 * m1;
  *reinterpret_cast<float2*>(mean + p2) = (float2){m0, m1};
  *reinterpret_cast<float2*>(rstd + p2) =
      (float2){rsqrtf(var0 + 1e-5f), rsqrtf(var1 + 1e-5f)};
}

// ---------------- split-bf16 MFMA LN+1x1 conv, pre-split weights ------------
// Round-2 proven staged structure, p-tile narrowed 128 -> 64:
// grid 256 x GB = 1024 blocks (4/CU), LDS 18.9KB, acc [4][2].
// Same float4 staging, same LDS B-split, same MFMA pass order ->
// bitwise-identical outputs; blocks cover disjoint pixel ranges.
__global__ __launch_bounds__(256) void k_conv1x1_mfma(
    const float* __restrict__ X,
    const unsigned short* __restrict__ Whi, const unsigned short* __restrict__ Wlo,
    const float* __restrict__ bias,
    const float* __restrict__ mean, const float* __restrict__ rstd,
    float* __restrict__ Y, int b0) {
  __shared__ __align__(16) float raw[32][68];    // X chunk [c][p], 64-wide
  __shared__ __align__(16) short Bh[64][40];     // Xn hi [p][c_local]
  __shared__ __align__(16) short Bl[64][40];
  const int bl = blockIdx.y;
  const int b = b0 + bl;
  const int p0 = blockIdx.x * 64;
  const int t = threadIdx.x;
  const int lane = t & 63, wv = t >> 6;
  const int quad = lane >> 4, l15 = lane & 15;
  const int wr = wv >> 1, wc = wv & 1;

  const int s1c = t >> 3, s1p = (t & 7) * 8;     // stage: 32 rows x 64 cols
  const int s2p = t & 63, s2o = t >> 6;          // split: 64 px x 4 octs
  const float mu = mean[b * HW + p0 + s2p];
  const float rs = rstd[b * HW + p0 + s2p];

  const float* Xb = X + ((size_t)b << 21);
  floatx4 acc[4][2];
#pragma unroll
  for (int i = 0; i < 4; ++i)
#pragma unroll
    for (int j = 0; j < 2; ++j) acc[i][j] = (floatx4){0.f, 0.f, 0.f, 0.f};

  for (int k0 = 0; k0 < 128; k0 += 32) {
    {
      const float* xp = Xb + ((size_t)(k0 + s1c) << 14) + p0 + s1p;
      *reinterpret_cast<float4*>(&raw[s1c][s1p]) =
          *reinterpret_cast<const float4*>(xp);
      *reinterpret_cast<float4*>(&raw[s1c][s1p + 4]) =
          *reinterpret_cast<const float4*>(xp + 4);
    }
    __syncthreads();
    {
      short th[8], tl[8];
#pragma unroll
      for (int jj = 0; jj < 8; ++jj) {
        float v = (raw[s2o * 8 + jj][s2p] - mu) * rs;
        unsigned short h = f2bf(v);
        th[jj] = (short)h;
        tl[jj] = (short)f2bf(v - bf2f(h));
      }
      *reinterpret_cast<bf16x8_t*>(&Bh[s2p][s2o * 8]) =
          *reinterpret_cast<bf16x8_t*>(&th[0]);
      *reinterpret_cast<bf16x8_t*>(&Bl[s2p][s2o * 8]) =
          *reinterpret_cast<bf16x8_t*>(&tl[0]);
    }
    __syncthreads();
    bf16x8_t afh[4], afl[4], bfh[2], bfl[2];
#pragma unroll
    for (int i = 0; i < 4; ++i) {
      const int m = wr * 64 + i * 16 + l15;
      afh[i] = *reinterpret_cast<const bf16x8_t*>(Whi + m * 128 + k0 + quad * 8);
      afl[i] = *reinterpret_cast<const bf16x8_t*>(Wlo + m * 128 + k0 + quad * 8);
    }
#pragma unroll
    for (int j = 0; j < 2; ++j) {
      const int p = wc * 32 + j * 16 + l15;
      bfh[j] = *reinterpret_cast<const bf16x8_t*>(&Bh[p][quad * 8]);
      bfl[j] = *reinterpret_cast<const bf16x8_t*>(&Bl[p][quad * 8]);
    }
#pragma unroll
    for (int i = 0; i < 4; ++i)
#pragma unroll
      for (int j = 0; j < 2; ++j) {
        acc[i][j] = __builtin_amdgcn_mfma_f32_16x16x32_bf16(afh[i], bfh[j], acc[i][j], 0, 0, 0);
        acc[i][j] = __builtin_amdgcn_mfma_f32_16x16x32_bf16(afh[i], bfl[j], acc[i][j], 0, 0, 0);
        acc[i][j] = __builtin_amdgcn_mfma_f32_16x16x32_bf16(afl[i], bfh[j], acc[i][j], 0, 0, 0);
      }
    __syncthreads();
  }
  float* Yb = Y + ((size_t)bl << 21);
#pragma unroll
  for (int i = 0; i < 4; ++i) {
#pragma unroll
    for (int j = 0; j < 2; ++j) {
#pragma unroll
      for (int r = 0; r < 4; ++r) {
        const int o = wr * 64 + i * 16 + quad * 4 + r;
        const int p = p0 + wc * 32 + j * 16 + l15;
        Yb[((size_t)o << 14) + p] = acc[i][j][r] + bias[o];
      }
    }
  }
}

// ---------------- split-bf16 MFMA score GEMM with fused depthwise 3x3 --------
// (round-2 proven version: one channel per block, unsplit 128x128 output)
__global__ __launch_bounds__(256) void k_score_mfma(
    const float* __restrict__ Yq, const float* __restrict__ Yk,
    const float* __restrict__ qdw, const float* __restrict__ qdb,
    const float* __restrict__ kdw, const float* __restrict__ kdb,
    float* __restrict__ P) {
  __shared__ __align__(16) float raw[32][132];   // dw out chunk [h][w]
  __shared__ __align__(16) short Ah[128][40];    // Q side [w][h] hi
  __shared__ __align__(16) short Al[128][40];
  __shared__ __align__(16) short Bh[128][40];    // K side [w][h] hi
  __shared__ __align__(16) short Bl[128][40];
  const int ch = blockIdx.x;
  const int bl = blockIdx.y;
  const int t = threadIdx.x;
  const int lane = t & 63, wv = t >> 6;
  const int quad = lane >> 4, l15 = lane & 15;
  const int wr = wv >> 1, wc = wv & 1;
  const int h_loc = t >> 3;
  const int w0 = (t & 7) * 16;
  const int s2w = t & 127, s2o = t >> 7;
  const int cc = ch;
  const float* Yqb = Yq + ((size_t)bl << 21) + ((size_t)cc << 14);
  const float* Ykb = Yk + ((size_t)bl << 21) + ((size_t)cc << 14);
  const float* qwt = qdw + cc * 9;
  const float* kwt = kdw + cc * 9;
  const float qbv = qdb[cc], kbv = kdb[cc];

  floatx4 acc[4][4];
#pragma unroll
  for (int i = 0; i < 4; ++i)
#pragma unroll
    for (int j = 0; j < 4; ++j) acc[i][j] = (floatx4){0.f, 0.f, 0.f, 0.f};

  for (int k0 = 0; k0 < 128; k0 += 32) {
    const int h = k0 + h_loc;
#pragma unroll
    for (int side = 0; side < 2; ++side) {
      // ---- fused dw 3x3: 16 contiguous w at view-row h ----
      const float* Yc = side ? Ykb : Yqb;
      const float* wt = side ? kwt : qwt;
      const float bias = side ? kbv : qbv;
      float a[16];
#pragma unroll
      for (int j = 0; j < 16; ++j) a[j] = bias;
#pragma unroll
      for (int dy = 0; dy < 3; ++dy) {
        const int hh = h + dy - 1;
        if (hh < 0 || hh > 127) continue;
        const float* rp = Yc + (hh << 7) + w0;
        float4 f0 = *reinterpret_cast<const float4*>(rp);
        float4 f1 = *reinterpret_cast<const float4*>(rp + 4);
        float4 f2 = *reinterpret_cast<const float4*>(rp + 8);
        float4 f3 = *reinterpret_cast<const float4*>(rp + 12);
        float s[18];
        s[1] = f0.x;  s[2] = f0.y;  s[3] = f0.z;  s[4] = f0.w;
        s[5] = f1.x;  s[6] = f1.y;  s[7] = f1.z;  s[8] = f1.w;
        s[9] = f2.x;  s[10] = f2.y; s[11] = f2.z; s[12] = f2.w;
        s[13] = f3.x; s[14] = f3.y; s[15] = f3.z; s[16] = f3.w;
        s[0] = (w0 > 0) ? rp[-1] : 0.f;
        s[17] = (w0 < 112) ? rp[16] : 0.f;
        const float wa = wt[dy * 3 + 0], wb = wt[dy * 3 + 1], wc2 = wt[dy * 3 + 2];
#pragma unroll
        for (int j = 0; j < 16; ++j)
          a[j] = fmaf(s[j], wa, fmaf(s[j + 1], wb, fmaf(s[j + 2], wc2, a[j])));
      }
#pragma unroll
      for (int u = 0; u < 4; ++u)
        *reinterpret_cast<float4*>(&raw[h_loc][w0 + 4 * u]) =
            (float4){a[4 * u], a[4 * u + 1], a[4 * u + 2], a[4 * u + 3]};
      __syncthreads();
      // ---- transpose [h][w] -> [w][h] + hi/lo split ----
      short* dh = side ? &Bh[0][0] : &Ah[0][0];
      short* dl = side ? &Bl[0][0] : &Al[0][0];
#pragma unroll
      for (int item = 0; item < 2; ++item) {
        const int oct = s2o + 2 * item;   // 0..3
        short th[8], tl[8];
#pragma unroll
        for (int jj = 0; jj < 8; ++jj) {
          float v = raw[oct * 8 + jj][s2w];
          unsigned short hb = f2bf(v);
          th[jj] = (short)hb;
          tl[jj] = (short)f2bf(v - bf2f(hb));
        }
        *reinterpret_cast<bf16x8_t*>(&dh[s2w * 40 + oct * 8]) =
            *reinterpret_cast<bf16x8_t*>(&th[0]);
        *reinterpret_cast<bf16x8_t*>(&dl[s2w * 40 + oct * 8]) =
            *reinterpret_cast<bf16x8_t*>(&tl[0]);
      }
      __syncthreads();
    }
    // ---- MFMA, 3 split passes ----
    bf16x8_t afh[4], afl[4], bfh[4], bfl[4];
#pragma unroll
    for (int i = 0; i < 4; ++i) {
      const int m = wr * 64 + i * 16 + l15;
      afh[i] = *reinterpret_cast<const bf16x8_t*>(&Ah[m][quad * 8]);
      afl[i] = *reinterpret_cast<const bf16x8_t*>(&Al[m][quad * 8]);
    }
#pragma unroll
    for (int j = 0; j < 4; ++j) {
      const int n = wc * 64 + j * 16 + l15;
      bfh[j] = *reinterpret_cast<const bf16x8_t*>(&Bh[n][quad * 8]);
      bfl[j] = *reinterpret_cast<const bf16x8_t*>(&Bl[n][quad * 8]);
    }
#pragma unroll
    for (int i = 0; i < 4; ++i)
#pragma unroll
      for (int j = 0; j < 4; ++j) {
        acc[i][j] = __builtin_amdgcn_mfma_f32_16x16x32_bf16(afh[i], bfh[j], acc[i][j], 0, 0, 0);
        acc[i][j] = __builtin_amdgcn_mfma_f32_16x16x32_bf16(afh[i], bfl[j], acc[i][j], 0, 0, 0);
        acc[i][j] = __builtin_amdgcn_mfma_f32_16x16x32_bf16(afl[i], bfh[j], acc[i][j], 0, 0, 0);
      }
  }
  float* Pp = P + ((size_t)(ch * GB + bl) << 14);
#pragma unroll
  for (int i = 0; i < 4; ++i) {
#pragma unroll
    for (int j = 0; j < 4; ++j) {
#pragma unroll
      for (int r = 0; r < 4; ++r) {
        const int c = wr * 64 + i * 16 + quad * 4 + r;
        const int d = wc * 64 + j * 16 + l15;
        Pp[c * 128 + d] = acc[i][j][r];
      }
    }
  }
}

// ---------------- fused: split-K reduce (128 partials) + softmax -> bf16 ----
__global__ __launch_bounds__(128) void k_reduce_softmax(
    const float* __restrict__ P, unsigned short* __restrict__ Sbf) {
  __shared__ float red[128];
  const int row = blockIdx.x;            // bl*128 + c
  const int bl = row >> 7, c = row & 127;
  const int t = threadIdx.x;
  const size_t rem = ((size_t)c << 7) + t;
  float v = 0.f;
  for (int ch = 0; ch < 128; ++ch)
    v += P[((size_t)(ch * GB + bl) << 14) + rem];
  red[t] = v;
  __syncthreads();
  for (int s = 64; s > 0; s >>= 1) {
    if (t < s) red[t] = fmaxf(red[t], red[t + s]);
    __syncthreads();
  }
  float mx = red[0];
  __syncthreads();
  float e = expf(v - mx);
  red[t] = e;
  __syncthreads();
  for (int s = 64; s > 0; s >>= 1) {
    if (t < s) red[t] += red[t + s];
    __syncthreads();
  }
  Sbf[((size_t)bl << 14) + rem] = f2bf(e / red[0]);
}

// ---------------- depthwise 3x3 + transpose: Vt[p][c] bf16 -----------------
__global__ __launch_bounds__(256) void k_dw_t(const float* __restrict__ Y,
                                              const float* __restrict__ Kw,
                                              const float* __restrict__ db,
                                              unsigned short* __restrict__ Vt) {
  __shared__ unsigned short T[128][33];
  const int h = blockIdx.x;
  const int c0 = blockIdx.y * 32;
  const int bl = blockIdx.z;
  const int t = threadIdx.x;
  const int cl = t >> 3;
  const int w0 = (t & 7) * 16;
  const int c = c0 + cl;
  const float* Yc = Y + ((size_t)bl << 21) + ((size_t)c << 14);
  const float* wt = Kw + c * 9;
  float a[16];
#pragma unroll
  for (int j = 0; j < 16; ++j) a[j] = db[c];
#pragma unroll
  for (int dy = 0; dy < 3; ++dy) {
    const int hh = h + dy - 1;
    if (hh < 0 || hh > 127) continue;
    const float* rp = Yc + (hh << 7) + w0;
    float4 f0 = *reinterpret_cast<const float4*>(rp);
    float4 f1 = *reinterpret_cast<const float4*>(rp + 4);
    float4 f2 = *reinterpret_cast<const float4*>(rp + 8);
    float4 f3 = *reinterpret_cast<const float4*>(rp + 12);
    float s[18];
    s[1] = f0.x;  s[2] = f0.y;  s[3] = f0.z;  s[4] = f0.w;
    s[5] = f1.x;  s[6] = f1.y;  s[7] = f1.z;  s[8] = f1.w;
    s[9] = f2.x;  s[10] = f2.y; s[11] = f2.z; s[12] = f2.w;
    s[13] = f3.x; s[14] = f3.y; s[15] = f3.z; s[16] = f3.w;
    s[0] = (w0 > 0) ? rp[-1] : 0.f;
    s[17] = (w0 < 112) ? rp[16] : 0.f;
    const float wa = wt[dy * 3 + 0], wb = wt[dy * 3 + 1], wc2 = wt[dy * 3 + 2];
#pragma unroll
    for (int j = 0; j < 16; ++j)
      a[j] = fmaf(s[j], wa, fmaf(s[j + 1], wb, fmaf(s[j + 2], wc2, a[j])));
  }
#pragma unroll
  for (int j = 0; j < 16; ++j) T[w0 + j][cl] = f2bf(a[j]);
  __syncthreads();
  const int w = t >> 1, half = t & 1;
  unsigned short tmp[16];
#pragma unroll
  for (int j = 0; j < 16; ++j) tmp[j] = T[w][half * 16 + j];
  uint4 v0, v1;
  unsigned* vp0 = reinterpret_cast<unsigned*>(&v0);
  unsigned* vp1 = reinterpret_cast<unsigned*>(&v1);
#pragma unroll
  for (int j = 0; j < 4; ++j) {
    vp0[j] = (unsigned)tmp[2 * j] | ((unsigned)tmp[2 * j + 1] << 16);
    vp1[j] = (unsigned)tmp[8 + 2 * j] | ((unsigned)tmp[8 + 2 * j + 1] << 16);
  }
  unsigned short* dst = Vt + ((size_t)bl << 21) + ((size_t)((h << 7) + w) << 7)
                        + c0 + half * 16;
  *reinterpret_cast<uint4*>(dst) = v0;
  *reinterpret_cast<uint4*>(dst + 8) = v1;
}

// ---------------- MFMA: O[c,p] = sum_d Att[c,d] * V[d,p] — LDS-free --------
__global__ __launch_bounds__(256) void k_av_mfma(
    const unsigned short* __restrict__ Sbf, const unsigned short* __restrict__ Vt,
    unsigned short* __restrict__ O) {
  const int bl = blockIdx.y;
  const int p0 = blockIdx.x * 128;
  const int t = threadIdx.x;
  const int lane = t & 63, wv = t >> 6;
  const int quad = lane >> 4, l15 = lane & 15;
  const int wr = wv >> 1, wc = wv & 1;
  const unsigned short* Sb = Sbf + ((size_t)bl << 14);
  floatx4 acc[4][4];
#pragma unroll
  for (int i = 0; i < 4; ++i)
#pragma unroll
    for (int j = 0; j < 4; ++j) acc[i][j] = (floatx4){0.f, 0.f, 0.f, 0.f};
  const unsigned short* Vb = Vt + ((size_t)bl << 21);
#pragma unroll
  for (int d0 = 0; d0 < 128; d0 += 32) {
    bf16x8_t af[4], bf[4];
#pragma unroll
    for (int i = 0; i < 4; ++i) {
      const int m = wr * 64 + i * 16 + l15;
      af[i] = *reinterpret_cast<const bf16x8_t*>(Sb + m * 128 + d0 + quad * 8);
    }
#pragma unroll
    for (int j = 0; j < 4; ++j) {
      const int p = p0 + wc * 64 + j * 16 + l15;
      bf[j] = *reinterpret_cast<const bf16x8_t*>(Vb + ((size_t)p << 7) + d0 + quad * 8);
    }
#pragma unroll
    for (int i = 0; i < 4; ++i)
#pragma unroll
      for (int j = 0; j < 4; ++j)
        acc[i][j] = __builtin_amdgcn_mfma_f32_16x16x32_bf16(af[i], bf[j], acc[i][j], 0, 0, 0);
  }
  unsigned short* Ob = O + ((size_t)bl << 21);
#pragma unroll
  for (int i = 0; i < 4; ++i) {
#pragma unroll
    for (int j = 0; j < 4; ++j) {
#pragma unroll
      for (int r = 0; r < 4; ++r) {
        const int c = wr * 64 + i * 16 + quad * 4 + r;
        const int p = p0 + wc * 64 + j * 16 + l15;
        Ob[((size_t)c << 14) + p] = f2bf(acc[i][j][r]);
      }
    }
  }
}

// ---------------- MFMA final: LDS-free, lw pre-converted to bf16 ------------
__global__ __launch_bounds__(256) void k_final2_mfma(
    const unsigned short* __restrict__ A1, const unsigned short* __restrict__ A2,
    const unsigned short* __restrict__ lwbf, const float* __restrict__ lb,
    const float* __restrict__ Fi, const float* __restrict__ Fw,
    float* __restrict__ out, int b0) {
  const int c2 = blockIdx.x;
  const int bl = blockIdx.y;
  const int b = b0 + bl;
  const int t = threadIdx.x;
  const int lane = t & 63, wv = t >> 6;
  const int quad = lane >> 4, l15 = lane & 15;
  const int wr = wv >> 1, wc = wv & 1;
  floatx4 acc[4][4];
#pragma unroll
  for (int i = 0; i < 4; ++i)
#pragma unroll
    for (int j = 0; j < 4; ++j) acc[i][j] = (floatx4){0.f, 0.f, 0.f, 0.f};
#pragma unroll
  for (int phase = 0; phase < 2; ++phase) {
    const unsigned short* Ub = (phase ? A2 : A1) + ((size_t)bl << 21) + c2 * 128;
#pragma unroll
    for (int d0 = 0; d0 < 128; d0 += 32) {
      bf16x8_t af[4], bf[4];
#pragma unroll
      for (int i = 0; i < 4; ++i) {
        const int m = wr * 64 + i * 16 + l15;
        af[i] = *reinterpret_cast<const bf16x8_t*>(
            lwbf + m * 256 + phase * 128 + d0 + quad * 8);
      }
#pragma unroll
      for (int j = 0; j < 4; ++j) {
        const int n = wc * 64 + j * 16 + l15;
        bf[j] = *reinterpret_cast<const bf16x8_t*>(Ub + ((size_t)n << 14) + d0 + quad * 8);
      }
#pragma unroll
      for (int i = 0; i < 4; ++i)
#pragma unroll
        for (int j = 0; j < 4; ++j)
          acc[i][j] = __builtin_amdgcn_mfma_f32_16x16x32_bf16(af[i], bf[j], acc[i][j], 0, 0, 0);
    }
  }
  const size_t obase = ((size_t)b << 21) + ((size_t)c2 << 14);
#pragma unroll
  for (int i = 0; i < 4; ++i) {
#pragma unroll
    for (int j = 0; j < 4; ++j) {
#pragma unroll
      for (int r = 0; r < 4; ++r) {
        const int h2 = wr * 64 + i * 16 + quad * 4 + r;
        const int w2 = wc * 64 + j * 16 + l15;
        const size_t a = obase + ((size_t)h2 << 7) + w2;
        out[a] = acc[i][j][r] + lb[h2] + Fi[a] + Fw[a];
      }
    }
  }
}

extern "C" void kernel_launch(void* const* d_in, const int* in_sizes, int n_in,
                              void* d_out, int out_size, void* d_ws, size_t ws_size,
                              hipStream_t stream) {
  const float* F_i  = (const float*)d_in[0];
  const float* F_w  = (const float*)d_in[1];
  const float* g1   = (const float*)d_in[2];
  const float* g2   = (const float*)d_in[3];
  const float* qw1  = (const float*)d_in[4];
  const float* kw1  = (const float*)d_in[5];
  const float* vw1  = (const float*)d_in[6];
  const float* qw2  = (const float*)d_in[7];
  const float* kw2  = (const float*)d_in[8];
  const float* vw2  = (const float*)d_in[9];
  const float* qb1  = (const float*)d_in[10];
  const float* kb1  = (const float*)d_in[11];
  const float* vb1  = (const float*)d_in[12];
  const float* qb2  = (const float*)d_in[13];
  const float* kb2  = (const float*)d_in[14];
  const float* vb2  = (const float*)d_in[15];
  const float* qdw1 = (const float*)d_in[16];
  const float* kdw1 = (const float*)d_in[17];
  const float* vdw1 = (const float*)d_in[18];
  const float* qdw2 = (const float*)d_in[19];
  const float* kdw2 = (const float*)d_in[20];
  const float* vdw2 = (const float*)d_in[21];
  const float* qdb1 = (const float*)d_in[22];
  const float* kdb1 = (const float*)d_in[23];
  const float* vdb1 = (const float*)d_in[24];
  const float* qdb2 = (const float*)d_in[25];
  const float* kdb2 = (const float*)d_in[26];
  const float* vdb2 = (const float*)d_in[27];
  const float* lw   = (const float*)d_in[28];
  const float* lb   = (const float*)d_in[29];
  float* out = (float*)d_out;

  // ---- workspace (~114.6 MiB peak; <=116 MiB proven safe) ----
  char* w = (char*)d_ws;
  const size_t NTOT = (size_t)NB * HW;                      // 131072
  float* meanI = (float*)w; w += NTOT * 4;
  float* rstdI = (float*)w; w += NTOT * 4;
  float* meanW = (float*)w; w += NTOT * 4;
  float* rstdW = (float*)w; w += NTOT * 4;
  unsigned short* Sbf = (unsigned short*)w; w += (size_t)GB * HW * 2;     // 128 KiB
  unsigned short* Wsplit = (unsigned short*)w; w += 6 * 32768 * 2;        // 384 KiB
  unsigned short* lwbf = (unsigned short*)w; w += 32768 * 2;              // 64 KiB
  float* P     = (float*)w; w += (size_t)128 * GB * HW * 4; // 32 MiB
  float* Yq    = (float*)w; w += ((size_t)GB << 21) * 4;    // 32 MiB
  char*  Ykreg = w;         w += ((size_t)GB << 21) * 4;    // 32 MiB (overlaid)
  float* Yk    = (float*)Ykreg;
  unsigned short* Vt = (unsigned short*)Ykreg;                            // 16 MiB
  unsigned short* A2 = (unsigned short*)(Ykreg + ((size_t)GB << 21) * 2); // 16 MiB
  unsigned short* A1 = (unsigned short*)w; w += ((size_t)GB << 21) * 2;   // 16 MiB

  // pre-split conv weights (W*g -> hi/lo bf16) and lw -> bf16
  const unsigned short* Wh0 = Wsplit + 0 * 32768;  // qw1*g1
  const unsigned short* Wh1 = Wsplit + 1 * 32768;  // kw1*g1
  const unsigned short* Wh2 = Wsplit + 2 * 32768;  // vw1*g1
  const unsigned short* Wh3 = Wsplit + 3 * 32768;  // qw2*g2
  const unsigned short* Wh4 = Wsplit + 4 * 32768;  // kw2*g2
  const unsigned short* Wh5 = Wsplit + 5 * 32768;  // vw2*g2

  dim3 blk(256);
  k_prep_w<<<dim3(8, 7), blk, 0, stream>>>(qw1, kw1, vw1, qw2, kw2, vw2,
                                           g1, g2, lw, Wsplit, lwbf);
  k_ln_stats<<<dim3(256), blk, 0, stream>>>(F_i, meanI, rstdI);
  k_ln_stats<<<dim3(256), blk, 0, stream>>>(F_w, meanW, rstdW);

  for (int b0 = 0; b0 < NB; b0 += GB) {
    // ---- attention 1: a1 = softmax(Qi^T Kw) ; Aw = a1 @ Vw -> A1 ----
    k_conv1x1_mfma<<<dim3(256, GB), blk, 0, stream>>>(F_i, Wh0, Wh0 + 16384, qb1, meanI, rstdI, Yq, b0);
    k_conv1x1_mfma<<<dim3(256, GB), blk, 0, stream>>>(F_w, Wh4, Wh4 + 16384, kb2, meanW, rstdW, Yk, b0);
    k_score_mfma<<<dim3(128, GB), blk, 0, stream>>>(Yq, Yk, qdw1, qdb1, kdw2, kdb2, P);
    k_reduce_softmax<<<dim3(GB * 128), dim3(128), 0, stream>>>(P, Sbf);
    k_conv1x1_mfma<<<dim3(256, GB), blk, 0, stream>>>(F_w, Wh5, Wh5 + 16384, vb2, meanW, rstdW, Yq, b0);
    k_dw_t<<<dim3(128, 4, GB), blk, 0, stream>>>(Yq, vdw2, vdb2, Vt);
    k_av_mfma<<<dim3(128, GB), blk, 0, stream>>>(Sbf, Vt, A1);

    // ---- attention 2: a2 = softmax(Qw^T Ki) ; Ai = a2 @ Vi -> A2 ----
    k_conv1x1_mfma<<<dim3(256, GB), blk, 0, stream>>>(F_w, Wh3, Wh3 + 16384, qb2, meanW, rstdW, Yq, b0);
    k_conv1x1_mfma<<<dim3(256, GB), blk, 0, stream>>>(F_i, Wh1, Wh1 + 16384, kb1, meanI, rstdI, Yk, b0);
    k_score_mfma<<<dim3(128, GB), blk, 0, stream>>>(Yq, Yk, qdw2, qdb2, kdw1, kdb1, P);
    k_reduce_softmax<<<dim3(GB * 128), dim3(128), 0, stream>>>(P, Sbf);
    k_conv1x1_mfma<<<dim3(256, GB), blk, 0, stream>>>(F_i, Wh2, Wh2 + 16384, vb1, meanI, rstdI, Yq, b0);
    k_dw_t<<<dim3(128, 4, GB), blk, 0, stream>>>(Yq, vdw1, vdb1, Vt);
    k_av_mfma<<<dim3(128, GB), blk, 0, stream>>>(Sbf, Vt, A2);

    // ---- fused final linear + residual (single out write) ----
    k_final2_mfma<<<dim3(128, GB), blk, 0, stream>>>(A1, A2, lwbf, lb, F_i, F_w, out, b0);
  }
}

// Round 6
// 796.503 us; speedup vs baseline: 1.1012x; 1.0828x over previous
//
#include <hip/hip_runtime.h>
#include <cstddef>
#include <cstring>

#define HW 16384
#define CC 128
#define NB 8
#define GB 4   // batches per group

typedef short bf16x8_t __attribute__((ext_vector_type(8)));
typedef float floatx4 __attribute__((ext_vector_type(4)));

__device__ inline unsigned short f2bf(float f) {
  unsigned u; __builtin_memcpy(&u, &f, 4);
  u += 0x7fffu + ((u >> 16) & 1u);
  return (unsigned short)(u >> 16);
}
__device__ inline float bf2f(unsigned short s) {
  unsigned u = ((unsigned)s) << 16; float f; __builtin_memcpy(&f, &u, 4);
  return f;
}

// ---------------- one-time weight prep: (W*g) -> hi/lo bf16; lw -> bf16 -----
__global__ __launch_bounds__(256) void k_prep_w(
    const float* __restrict__ qw1, const float* __restrict__ kw1,
    const float* __restrict__ vw1, const float* __restrict__ qw2,
    const float* __restrict__ kw2, const float* __restrict__ vw2,
    const float* __restrict__ g1, const float* __restrict__ g2,
    const float* __restrict__ lw,
    unsigned short* __restrict__ Wsplit, unsigned short* __restrict__ lwbf) {
  const int t = threadIdx.x;
  const int m = blockIdx.y;
  if (m < 6) {
    const float* W = (m == 0) ? qw1 : (m == 1) ? kw1 : (m == 2) ? vw1
                   : (m == 3) ? qw2 : (m == 4) ? kw2 : vw2;
    const float* g = (m < 3) ? g1 : g2;
    const int idx = blockIdx.x * 256 + t;     // 0..2047
    const int o = idx >> 4;
    const int c0 = (idx & 15) * 8;
    unsigned short* hi = Wsplit + m * 32768 + o * 128 + c0;
    unsigned short* lo = hi + 16384;
#pragma unroll
    for (int j = 0; j < 8; ++j) {
      float v = W[o * 128 + c0 + j] * g[c0 + j];
      unsigned short h = f2bf(v);
      hi[j] = h;
      lo[j] = f2bf(v - bf2f(h));
    }
  } else {
    const int idx = blockIdx.x * 256 + t;     // 0..2047 (x16 elems = 32768)
#pragma unroll
    for (int j = 0; j < 16; ++j)
      lwbf[idx * 16 + j] = f2bf(lw[idx * 16 + j]);
  }
}

// ---------------- LayerNorm stats, both inputs in ONE dispatch --------------
// blockIdx.y selects F_i / F_w; float2-vectorized, same per-element FP order.
__global__ __launch_bounds__(256) void k_ln_stats2(
    const float* __restrict__ xi, const float* __restrict__ xw,
    float* __restrict__ meanI, float* __restrict__ rstdI,
    float* __restrict__ meanW, float* __restrict__ rstdW) {
  const int which = blockIdx.y;
  const float* x = which ? xw : xi;
  float* mean = which ? meanW : meanI;
  float* rstd = which ? rstdW : rstdI;
  int idx = blockIdx.x * 256 + threadIdx.x;   // 0 .. 65535
  int p2 = idx * 2;
  int b = p2 >> 14;
  int p = p2 & (HW - 1);
  const float* xp = x + ((size_t)b << 21) + p;
  float s0 = 0.f, ss0 = 0.f, s1 = 0.f, ss1 = 0.f;
  for (int c = 0; c < CC; ++c) {
    float2 v = *reinterpret_cast<const float2*>(xp + ((size_t)c << 14));
    s0 += v.x; ss0 += v.x * v.x;
    s1 += v.y; ss1 += v.y * v.y;
  }
  float m0 = s0 * (1.0f / CC), m1 = s1 * (1.0f / CC);
  float var0 = ss0 * (1.0f / CC) - m0 * m0;
  float var1 = ss1 * (1.0f / CC) - m1 * m1;
  *reinterpret_cast<float2*>(mean + p2) = (float2){m0, m1};
  *reinterpret_cast<float2*>(rstd + p2) =
      (float2){rsqrtf(var0 + 1e-5f), rsqrtf(var1 + 1e-5f)};
}

// ---------------- conv1x1 per-block body (round-2 proven, 128-wide) --------
__device__ __forceinline__ void conv_body(
    const float* __restrict__ X,
    const unsigned short* __restrict__ Whi, const unsigned short* __restrict__ Wlo,
    const float* __restrict__ bias,
    const float* __restrict__ mean, const float* __restrict__ rstd,
    float* __restrict__ Y, int b0, int bl, int p0,
    float (*raw)[132], short (*Bh)[40], short (*Bl)[40]) {
  const int b = b0 + bl;
  const int t = threadIdx.x;
  const int lane = t & 63, wv = t >> 6;
  const int quad = lane >> 4, l15 = lane & 15;
  const int wr = wv >> 1, wc = wv & 1;

  const int s1c = t >> 3, s1p = (t & 7) * 16;
  const int s2p = t & 127, s2o = t >> 7;
  const float mu = mean[b * HW + p0 + s2p];
  const float rs = rstd[b * HW + p0 + s2p];

  const float* Xb = X + ((size_t)b << 21);
  floatx4 acc[4][4];
#pragma unroll
  for (int i = 0; i < 4; ++i)
#pragma unroll
    for (int j = 0; j < 4; ++j) acc[i][j] = (floatx4){0.f, 0.f, 0.f, 0.f};

  for (int k0 = 0; k0 < 128; k0 += 32) {
    {
      const float* xp = Xb + ((size_t)(k0 + s1c) << 14) + p0 + s1p;
#pragma unroll
      for (int u = 0; u < 4; ++u)
        *reinterpret_cast<float4*>(&raw[s1c][s1p + 4 * u]) =
            *reinterpret_cast<const float4*>(xp + 4 * u);
    }
    __syncthreads();
#pragma unroll
    for (int item = 0; item < 2; ++item) {
      const int oct = s2o + 2 * item;     // 0..3
      short th[8], tl[8];
#pragma unroll
      for (int jj = 0; jj < 8; ++jj) {
        float v = (raw[oct * 8 + jj][s2p] - mu) * rs;
        unsigned short h = f2bf(v);
        th[jj] = (short)h;
        tl[jj] = (short)f2bf(v - bf2f(h));
      }
      *reinterpret_cast<bf16x8_t*>(&Bh[s2p][oct * 8]) =
          *reinterpret_cast<bf16x8_t*>(&th[0]);
      *reinterpret_cast<bf16x8_t*>(&Bl[s2p][oct * 8]) =
          *reinterpret_cast<bf16x8_t*>(&tl[0]);
    }
    __syncthreads();
    bf16x8_t afh[4], afl[4], bfh[4], bfl[4];
#pragma unroll
    for (int i = 0; i < 4; ++i) {
      const int m = wr * 64 + i * 16 + l15;
      afh[i] = *reinterpret_cast<const bf16x8_t*>(Whi + m * 128 + k0 + quad * 8);
      afl[i] = *reinterpret_cast<const bf16x8_t*>(Wlo + m * 128 + k0 + quad * 8);
    }
#pragma unroll
    for (int j = 0; j < 4; ++j) {
      const int p = wc * 64 + j * 16 + l15;
      bfh[j] = *reinterpret_cast<const bf16x8_t*>(&Bh[p][quad * 8]);
      bfl[j] = *reinterpret_cast<const bf16x8_t*>(&Bl[p][quad * 8]);
    }
#pragma unroll
    for (int i = 0; i < 4; ++i)
#pragma unroll
      for (int j = 0; j < 4; ++j) {
        acc[i][j] = __builtin_amdgcn_mfma_f32_16x16x32_bf16(afh[i], bfh[j], acc[i][j], 0, 0, 0);
        acc[i][j] = __builtin_amdgcn_mfma_f32_16x16x32_bf16(afh[i], bfl[j], acc[i][j], 0, 0, 0);
        acc[i][j] = __builtin_amdgcn_mfma_f32_16x16x32_bf16(afl[i], bfh[j], acc[i][j], 0, 0, 0);
      }
    __syncthreads();
  }
  float* Yb = Y + ((size_t)bl << 21);
#pragma unroll
  for (int i = 0; i < 4; ++i) {
#pragma unroll
    for (int j = 0; j < 4; ++j) {
#pragma unroll
      for (int r = 0; r < 4; ++r) {
        const int o = wr * 64 + i * 16 + quad * 4 + r;
        const int p = p0 + wc * 64 + j * 16 + l15;
        Yb[((size_t)o << 14) + p] = acc[i][j][r] + bias[o];
      }
    }
  }
}

// single conv (V path)
__global__ __launch_bounds__(256) void k_conv1x1_mfma(
    const float* __restrict__ X,
    const unsigned short* __restrict__ Whi, const unsigned short* __restrict__ Wlo,
    const float* __restrict__ bias,
    const float* __restrict__ mean, const float* __restrict__ rstd,
    float* __restrict__ Y, int b0) {
  __shared__ __align__(16) float raw[32][132];
  __shared__ __align__(16) short Bh[128][40];
  __shared__ __align__(16) short Bl[128][40];
  conv_body(X, Whi, Wlo, bias, mean, rstd, Y, b0,
            blockIdx.y, blockIdx.x * 128, raw, Bh, Bl);
}

// fused Q+K convs: blockIdx.z selects the parameter set. Per-block code is
// byte-identical to k_conv1x1_mfma; 1024 blocks co-resident -> 4 blocks/CU.
__global__ __launch_bounds__(256) void k_convQK_mfma(
    const float* __restrict__ Xq,
    const unsigned short* __restrict__ Wqhi, const unsigned short* __restrict__ Wqlo,
    const float* __restrict__ qbias,
    const float* __restrict__ meanq, const float* __restrict__ rstdq,
    float* __restrict__ Yq,
    const float* __restrict__ Xk,
    const unsigned short* __restrict__ Wkhi, const unsigned short* __restrict__ Wklo,
    const float* __restrict__ kbias,
    const float* __restrict__ meank, const float* __restrict__ rstdk,
    float* __restrict__ Yk, int b0) {
  __shared__ __align__(16) float raw[32][132];
  __shared__ __align__(16) short Bh[128][40];
  __shared__ __align__(16) short Bl[128][40];
  const int z = blockIdx.z;
  conv_body(z ? Xk : Xq, z ? Wkhi : Wqhi, z ? Wklo : Wqlo,
            z ? kbias : qbias, z ? meank : meanq, z ? rstdk : rstdq,
            z ? Yk : Yq, b0, blockIdx.y, blockIdx.x * 128, raw, Bh, Bl);
}

// ---------------- split-bf16 MFMA score GEMM with fused depthwise 3x3 --------
// (round-2 proven version: one channel per block, unsplit 128x128 output)
__global__ __launch_bounds__(256) void k_score_mfma(
    const float* __restrict__ Yq, const float* __restrict__ Yk,
    const float* __restrict__ qdw, const float* __restrict__ qdb,
    const float* __restrict__ kdw, const float* __restrict__ kdb,
    float* __restrict__ P) {
  __shared__ __align__(16) float raw[32][132];   // dw out chunk [h][w]
  __shared__ __align__(16) short Ah[128][40];    // Q side [w][h] hi
  __shared__ __align__(16) short Al[128][40];
  __shared__ __align__(16) short Bh[128][40];    // K side [w][h] hi
  __shared__ __align__(16) short Bl[128][40];
  const int ch = blockIdx.x;
  const int bl = blockIdx.y;
  const int t = threadIdx.x;
  const int lane = t & 63, wv = t >> 6;
  const int quad = lane >> 4, l15 = lane & 15;
  const int wr = wv >> 1, wc = wv & 1;
  const int h_loc = t >> 3;
  const int w0 = (t & 7) * 16;
  const int s2w = t & 127, s2o = t >> 7;
  const int cc = ch;
  const float* Yqb = Yq + ((size_t)bl << 21) + ((size_t)cc << 14);
  const float* Ykb = Yk + ((size_t)bl << 21) + ((size_t)cc << 14);
  const float* qwt = qdw + cc * 9;
  const float* kwt = kdw + cc * 9;
  const float qbv = qdb[cc], kbv = kdb[cc];

  floatx4 acc[4][4];
#pragma unroll
  for (int i = 0; i < 4; ++i)
#pragma unroll
    for (int j = 0; j < 4; ++j) acc[i][j] = (floatx4){0.f, 0.f, 0.f, 0.f};

  for (int k0 = 0; k0 < 128; k0 += 32) {
    const int h = k0 + h_loc;
#pragma unroll
    for (int side = 0; side < 2; ++side) {
      // ---- fused dw 3x3: 16 contiguous w at view-row h ----
      const float* Yc = side ? Ykb : Yqb;
      const float* wt = side ? kwt : qwt;
      const float bias = side ? kbv : qbv;
      float a[16];
#pragma unroll
      for (int j = 0; j < 16; ++j) a[j] = bias;
#pragma unroll
      for (int dy = 0; dy < 3; ++dy) {
        const int hh = h + dy - 1;
        if (hh < 0 || hh > 127) continue;
        const float* rp = Yc + (hh << 7) + w0;
        float4 f0 = *reinterpret_cast<const float4*>(rp);
        float4 f1 = *reinterpret_cast<const float4*>(rp + 4);
        float4 f2 = *reinterpret_cast<const float4*>(rp + 8);
        float4 f3 = *reinterpret_cast<const float4*>(rp + 12);
        float s[18];
        s[1] = f0.x;  s[2] = f0.y;  s[3] = f0.z;  s[4] = f0.w;
        s[5] = f1.x;  s[6] = f1.y;  s[7] = f1.z;  s[8] = f1.w;
        s[9] = f2.x;  s[10] = f2.y; s[11] = f2.z; s[12] = f2.w;
        s[13] = f3.x; s[14] = f3.y; s[15] = f3.z; s[16] = f3.w;
        s[0] = (w0 > 0) ? rp[-1] : 0.f;
        s[17] = (w0 < 112) ? rp[16] : 0.f;
        const float wa = wt[dy * 3 + 0], wb = wt[dy * 3 + 1], wc2 = wt[dy * 3 + 2];
#pragma unroll
        for (int j = 0; j < 16; ++j)
          a[j] = fmaf(s[j], wa, fmaf(s[j + 1], wb, fmaf(s[j + 2], wc2, a[j])));
      }
#pragma unroll
      for (int u = 0; u < 4; ++u)
        *reinterpret_cast<float4*>(&raw[h_loc][w0 + 4 * u]) =
            (float4){a[4 * u], a[4 * u + 1], a[4 * u + 2], a[4 * u + 3]};
      __syncthreads();
      // ---- transpose [h][w] -> [w][h] + hi/lo split ----
      short* dh = side ? &Bh[0][0] : &Ah[0][0];
      short* dl = side ? &Bl[0][0] : &Al[0][0];
#pragma unroll
      for (int item = 0; item < 2; ++item) {
        const int oct = s2o + 2 * item;   // 0..3
        short th[8], tl[8];
#pragma unroll
        for (int jj = 0; jj < 8; ++jj) {
          float v = raw[oct * 8 + jj][s2w];
          unsigned short hb = f2bf(v);
          th[jj] = (short)hb;
          tl[jj] = (short)f2bf(v - bf2f(hb));
        }
        *reinterpret_cast<bf16x8_t*>(&dh[s2w * 40 + oct * 8]) =
            *reinterpret_cast<bf16x8_t*>(&th[0]);
        *reinterpret_cast<bf16x8_t*>(&dl[s2w * 40 + oct * 8]) =
            *reinterpret_cast<bf16x8_t*>(&tl[0]);
      }
      __syncthreads();
    }
    // ---- MFMA, 3 split passes ----
    bf16x8_t afh[4], afl[4], bfh[4], bfl[4];
#pragma unroll
    for (int i = 0; i < 4; ++i) {
      const int m = wr * 64 + i * 16 + l15;
      afh[i] = *reinterpret_cast<const bf16x8_t*>(&Ah[m][quad * 8]);
      afl[i] = *reinterpret_cast<const bf16x8_t*>(&Al[m][quad * 8]);
    }
#pragma unroll
    for (int j = 0; j < 4; ++j) {
      const int n = wc * 64 + j * 16 + l15;
      bfh[j] = *reinterpret_cast<const bf16x8_t*>(&Bh[n][quad * 8]);
      bfl[j] = *reinterpret_cast<const bf16x8_t*>(&Bl[n][quad * 8]);
    }
#pragma unroll
    for (int i = 0; i < 4; ++i)
#pragma unroll
      for (int j = 0; j < 4; ++j) {
        acc[i][j] = __builtin_amdgcn_mfma_f32_16x16x32_bf16(afh[i], bfh[j], acc[i][j], 0, 0, 0);
        acc[i][j] = __builtin_amdgcn_mfma_f32_16x16x32_bf16(afh[i], bfl[j], acc[i][j], 0, 0, 0);
        acc[i][j] = __builtin_amdgcn_mfma_f32_16x16x32_bf16(afl[i], bfh[j], acc[i][j], 0, 0, 0);
      }
  }
  float* Pp = P + ((size_t)(ch * GB + bl) << 14);
#pragma unroll
  for (int i = 0; i < 4; ++i) {
#pragma unroll
    for (int j = 0; j < 4; ++j) {
#pragma unroll
      for (int r = 0; r < 4; ++r) {
        const int c = wr * 64 + i * 16 + quad * 4 + r;
        const int d = wc * 64 + j * 16 + l15;
        Pp[c * 128 + d] = acc[i][j][r];
      }
    }
  }
}

// ---------------- fused: split-K reduce (128 partials) + softmax -> bf16 ----
__global__ __launch_bounds__(128) void k_reduce_softmax(
    const float* __restrict__ P, unsigned short* __restrict__ Sbf) {
  __shared__ float red[128];
  const int row = blockIdx.x;            // bl*128 + c
  const int bl = row >> 7, c = row & 127;
  const int t = threadIdx.x;
  const size_t rem = ((size_t)c << 7) + t;
  float v = 0.f;
  for (int ch = 0; ch < 128; ++ch)
    v += P[((size_t)(ch * GB + bl) << 14) + rem];
  red[t] = v;
  __syncthreads();
  for (int s = 64; s > 0; s >>= 1) {
    if (t < s) red[t] = fmaxf(red[t], red[t + s]);
    __syncthreads();
  }
  float mx = red[0];
  __syncthreads();
  float e = expf(v - mx);
  red[t] = e;
  __syncthreads();
  for (int s = 64; s > 0; s >>= 1) {
    if (t < s) red[t] += red[t + s];
    __syncthreads();
  }
  Sbf[((size_t)bl << 14) + rem] = f2bf(e / red[0]);
}

// ---------------- depthwise 3x3 + transpose: Vt[p][c] bf16 -----------------
__global__ __launch_bounds__(256) void k_dw_t(const float* __restrict__ Y,
                                              const float* __restrict__ Kw,
                                              const float* __restrict__ db,
                                              unsigned short* __restrict__ Vt) {
  __shared__ unsigned short T[128][33];
  const int h = blockIdx.x;
  const int c0 = blockIdx.y * 32;
  const int bl = blockIdx.z;
  const int t = threadIdx.x;
  const int cl = t >> 3;
  const int w0 = (t & 7) * 16;
  const int c = c0 + cl;
  const float* Yc = Y + ((size_t)bl << 21) + ((size_t)c << 14);
  const float* wt = Kw + c * 9;
  float a[16];
#pragma unroll
  for (int j = 0; j < 16; ++j) a[j] = db[c];
#pragma unroll
  for (int dy = 0; dy < 3; ++dy) {
    const int hh = h + dy - 1;
    if (hh < 0 || hh > 127) continue;
    const float* rp = Yc + (hh << 7) + w0;
    float4 f0 = *reinterpret_cast<const float4*>(rp);
    float4 f1 = *reinterpret_cast<const float4*>(rp + 4);
    float4 f2 = *reinterpret_cast<const float4*>(rp + 8);
    float4 f3 = *reinterpret_cast<const float4*>(rp + 12);
    float s[18];
    s[1] = f0.x;  s[2] = f0.y;  s[3] = f0.z;  s[4] = f0.w;
    s[5] = f1.x;  s[6] = f1.y;  s[7] = f1.z;  s[8] = f1.w;
    s[9] = f2.x;  s[10] = f2.y; s[11] = f2.z; s[12] = f2.w;
    s[13] = f3.x; s[14] = f3.y; s[15] = f3.z; s[16] = f3.w;
    s[0] = (w0 > 0) ? rp[-1] : 0.f;
    s[17] = (w0 < 112) ? rp[16] : 0.f;
    const float wa = wt[dy * 3 + 0], wb = wt[dy * 3 + 1], wc2 = wt[dy * 3 + 2];
#pragma unroll
    for (int j = 0; j < 16; ++j)
      a[j] = fmaf(s[j], wa, fmaf(s[j + 1], wb, fmaf(s[j + 2], wc2, a[j])));
  }
#pragma unroll
  for (int j = 0; j < 16; ++j) T[w0 + j][cl] = f2bf(a[j]);
  __syncthreads();
  const int w = t >> 1, half = t & 1;
  unsigned short tmp[16];
#pragma unroll
  for (int j = 0; j < 16; ++j) tmp[j] = T[w][half * 16 + j];
  uint4 v0, v1;
  unsigned* vp0 = reinterpret_cast<unsigned*>(&v0);
  unsigned* vp1 = reinterpret_cast<unsigned*>(&v1);
#pragma unroll
  for (int j = 0; j < 4; ++j) {
    vp0[j] = (unsigned)tmp[2 * j] | ((unsigned)tmp[2 * j + 1] << 16);
    vp1[j] = (unsigned)tmp[8 + 2 * j] | ((unsigned)tmp[8 + 2 * j + 1] << 16);
  }
  unsigned short* dst = Vt + ((size_t)bl << 21) + ((size_t)((h << 7) + w) << 7)
                        + c0 + half * 16;
  *reinterpret_cast<uint4*>(dst) = v0;
  *reinterpret_cast<uint4*>(dst + 8) = v1;
}

// ---------------- MFMA: O[c,p] = sum_d Att[c,d] * V[d,p] — LDS-free --------
__global__ __launch_bounds__(256) void k_av_mfma(
    const unsigned short* __restrict__ Sbf, const unsigned short* __restrict__ Vt,
    unsigned short* __restrict__ O) {
  const int bl = blockIdx.y;
  const int p0 = blockIdx.x * 128;
  const int t = threadIdx.x;
  const int lane = t & 63, wv = t >> 6;
  const int quad = lane >> 4, l15 = lane & 15;
  const int wr = wv >> 1, wc = wv & 1;
  const unsigned short* Sb = Sbf + ((size_t)bl << 14);
  floatx4 acc[4][4];
#pragma unroll
  for (int i = 0; i < 4; ++i)
#pragma unroll
    for (int j = 0; j < 4; ++j) acc[i][j] = (floatx4){0.f, 0.f, 0.f, 0.f};
  const unsigned short* Vb = Vt + ((size_t)bl << 21);
#pragma unroll
  for (int d0 = 0; d0 < 128; d0 += 32) {
    bf16x8_t af[4], bf[4];
#pragma unroll
    for (int i = 0; i < 4; ++i) {
      const int m = wr * 64 + i * 16 + l15;
      af[i] = *reinterpret_cast<const bf16x8_t*>(Sb + m * 128 + d0 + quad * 8);
    }
#pragma unroll
    for (int j = 0; j < 4; ++j) {
      const int p = p0 + wc * 64 + j * 16 + l15;
      bf[j] = *reinterpret_cast<const bf16x8_t*>(Vb + ((size_t)p << 7) + d0 + quad * 8);
    }
#pragma unroll
    for (int i = 0; i < 4; ++i)
#pragma unroll
      for (int j = 0; j < 4; ++j)
        acc[i][j] = __builtin_amdgcn_mfma_f32_16x16x32_bf16(af[i], bf[j], acc[i][j], 0, 0, 0);
  }
  unsigned short* Ob = O + ((size_t)bl << 21);
#pragma unroll
  for (int i = 0; i < 4; ++i) {
#pragma unroll
    for (int j = 0; j < 4; ++j) {
#pragma unroll
      for (int r = 0; r < 4; ++r) {
        const int c = wr * 64 + i * 16 + quad * 4 + r;
        const int p = p0 + wc * 64 + j * 16 + l15;
        Ob[((size_t)c << 14) + p] = f2bf(acc[i][j][r]);
      }
    }
  }
}

// ---------------- MFMA final: LDS-free, lw pre-converted to bf16 ------------
__global__ __launch_bounds__(256) void k_final2_mfma(
    const unsigned short* __restrict__ A1, const unsigned short* __restrict__ A2,
    const unsigned short* __restrict__ lwbf, const float* __restrict__ lb,
    const float* __restrict__ Fi, const float* __restrict__ Fw,
    float* __restrict__ out, int b0) {
  const int c2 = blockIdx.x;
  const int bl = blockIdx.y;
  const int b = b0 + bl;
  const int t = threadIdx.x;
  const int lane = t & 63, wv = t >> 6;
  const int quad = lane >> 4, l15 = lane & 15;
  const int wr = wv >> 1, wc = wv & 1;
  floatx4 acc[4][4];
#pragma unroll
  for (int i = 0; i < 4; ++i)
#pragma unroll
    for (int j = 0; j < 4; ++j) acc[i][j] = (floatx4){0.f, 0.f, 0.f, 0.f};
#pragma unroll
  for (int phase = 0; phase < 2; ++phase) {
    const unsigned short* Ub = (phase ? A2 : A1) + ((size_t)bl << 21) + c2 * 128;
#pragma unroll
    for (int d0 = 0; d0 < 128; d0 += 32) {
      bf16x8_t af[4], bf[4];
#pragma unroll
      for (int i = 0; i < 4; ++i) {
        const int m = wr * 64 + i * 16 + l15;
        af[i] = *reinterpret_cast<const bf16x8_t*>(
            lwbf + m * 256 + phase * 128 + d0 + quad * 8);
      }
#pragma unroll
      for (int j = 0; j < 4; ++j) {
        const int n = wc * 64 + j * 16 + l15;
        bf[j] = *reinterpret_cast<const bf16x8_t*>(Ub + ((size_t)n << 14) + d0 + quad * 8);
      }
#pragma unroll
      for (int i = 0; i < 4; ++i)
#pragma unroll
        for (int j = 0; j < 4; ++j)
          acc[i][j] = __builtin_amdgcn_mfma_f32_16x16x32_bf16(af[i], bf[j], acc[i][j], 0, 0, 0);
    }
  }
  const size_t obase = ((size_t)b << 21) + ((size_t)c2 << 14);
#pragma unroll
  for (int i = 0; i < 4; ++i) {
#pragma unroll
    for (int j = 0; j < 4; ++j) {
#pragma unroll
      for (int r = 0; r < 4; ++r) {
        const int h2 = wr * 64 + i * 16 + quad * 4 + r;
        const int w2 = wc * 64 + j * 16 + l15;
        const size_t a = obase + ((size_t)h2 << 7) + w2;
        out[a] = acc[i][j][r] + lb[h2] + Fi[a] + Fw[a];
      }
    }
  }
}

extern "C" void kernel_launch(void* const* d_in, const int* in_sizes, int n_in,
                              void* d_out, int out_size, void* d_ws, size_t ws_size,
                              hipStream_t stream) {
  const float* F_i  = (const float*)d_in[0];
  const float* F_w  = (const float*)d_in[1];
  const float* g1   = (const float*)d_in[2];
  const float* g2   = (const float*)d_in[3];
  const float* qw1  = (const float*)d_in[4];
  const float* kw1  = (const float*)d_in[5];
  const float* vw1  = (const float*)d_in[6];
  const float* qw2  = (const float*)d_in[7];
  const float* kw2  = (const float*)d_in[8];
  const float* vw2  = (const float*)d_in[9];
  const float* qb1  = (const float*)d_in[10];
  const float* kb1  = (const float*)d_in[11];
  const float* vb1  = (const float*)d_in[12];
  const float* qb2  = (const float*)d_in[13];
  const float* kb2  = (const float*)d_in[14];
  const float* vb2  = (const float*)d_in[15];
  const float* qdw1 = (const float*)d_in[16];
  const float* kdw1 = (const float*)d_in[17];
  const float* vdw1 = (const float*)d_in[18];
  const float* qdw2 = (const float*)d_in[19];
  const float* kdw2 = (const float*)d_in[20];
  const float* vdw2 = (const float*)d_in[21];
  const float* qdb1 = (const float*)d_in[22];
  const float* kdb1 = (const float*)d_in[23];
  const float* vdb1 = (const float*)d_in[24];
  const float* qdb2 = (const float*)d_in[25];
  const float* kdb2 = (const float*)d_in[26];
  const float* vdb2 = (const float*)d_in[27];
  const float* lw   = (const float*)d_in[28];
  const float* lb   = (const float*)d_in[29];
  float* out = (float*)d_out;

  // ---- workspace (~114.6 MiB peak; <=116 MiB proven safe) ----
  char* w = (char*)d_ws;
  const size_t NTOT = (size_t)NB * HW;                      // 131072
  float* meanI = (float*)w; w += NTOT * 4;
  float* rstdI = (float*)w; w += NTOT * 4;
  float* meanW = (float*)w; w += NTOT * 4;
  float* rstdW = (float*)w; w += NTOT * 4;
  unsigned short* Sbf = (unsigned short*)w; w += (size_t)GB * HW * 2;     // 128 KiB
  unsigned short* Wsplit = (unsigned short*)w; w += 6 * 32768 * 2;        // 384 KiB
  unsigned short* lwbf = (unsigned short*)w; w += 32768 * 2;              // 64 KiB
  float* P     = (float*)w; w += (size_t)128 * GB * HW * 4; // 32 MiB
  float* Yq    = (float*)w; w += ((size_t)GB << 21) * 4;    // 32 MiB
  char*  Ykreg = w;         w += ((size_t)GB << 21) * 4;    // 32 MiB (overlaid)
  float* Yk    = (float*)Ykreg;
  unsigned short* Vt = (unsigned short*)Ykreg;                            // 16 MiB
  unsigned short* A2 = (unsigned short*)(Ykreg + ((size_t)GB << 21) * 2); // 16 MiB
  unsigned short* A1 = (unsigned short*)w; w += ((size_t)GB << 21) * 2;   // 16 MiB

  // pre-split conv weights (W*g -> hi/lo bf16) and lw -> bf16
  const unsigned short* Wh0 = Wsplit + 0 * 32768;  // qw1*g1
  const unsigned short* Wh1 = Wsplit + 1 * 32768;  // kw1*g1
  const unsigned short* Wh2 = Wsplit + 2 * 32768;  // vw1*g1
  const unsigned short* Wh3 = Wsplit + 3 * 32768;  // qw2*g2
  const unsigned short* Wh4 = Wsplit + 4 * 32768;  // kw2*g2
  const unsigned short* Wh5 = Wsplit + 5 * 32768;  // vw2*g2

  dim3 blk(256);
  k_prep_w<<<dim3(8, 7), blk, 0, stream>>>(qw1, kw1, vw1, qw2, kw2, vw2,
                                           g1, g2, lw, Wsplit, lwbf);
  k_ln_stats2<<<dim3(256, 2), blk, 0, stream>>>(F_i, F_w, meanI, rstdI, meanW, rstdW);

  for (int b0 = 0; b0 < NB; b0 += GB) {
    // ---- attention 1: a1 = softmax(Qi^T Kw) ; Aw = a1 @ Vw -> A1 ----
    k_convQK_mfma<<<dim3(128, GB, 2), blk, 0, stream>>>(
        F_i, Wh0, Wh0 + 16384, qb1, meanI, rstdI, Yq,
        F_w, Wh4, Wh4 + 16384, kb2, meanW, rstdW, Yk, b0);
    k_score_mfma<<<dim3(128, GB), blk, 0, stream>>>(Yq, Yk, qdw1, qdb1, kdw2, kdb2, P);
    k_reduce_softmax<<<dim3(GB * 128), dim3(128), 0, stream>>>(P, Sbf);
    k_conv1x1_mfma<<<dim3(128, GB), blk, 0, stream>>>(F_w, Wh5, Wh5 + 16384, vb2, meanW, rstdW, Yq, b0);
    k_dw_t<<<dim3(128, 4, GB), blk, 0, stream>>>(Yq, vdw2, vdb2, Vt);
    k_av_mfma<<<dim3(128, GB), blk, 0, stream>>>(Sbf, Vt, A1);

    // ---- attention 2: a2 = softmax(Qw^T Ki) ; Ai = a2 @ Vi -> A2 ----
    k_convQK_mfma<<<dim3(128, GB, 2), blk, 0, stream>>>(
        F_w, Wh3, Wh3 + 16384, qb2, meanW, rstdW, Yq,
        F_i, Wh1, Wh1 + 16384, kb1, meanI, rstdI, Yk, b0);
    k_score_mfma<<<dim3(128, GB), blk, 0, stream>>>(Yq, Yk, qdw2, qdb2, kdw1, kdb1, P);
    k_reduce_softmax<<<dim3(GB * 128), dim3(128), 0, stream>>>(P, Sbf);
    k_conv1x1_mfma<<<dim3(128, GB), blk, 0, stream>>>(F_i, Wh2, Wh2 + 16384, vb1, meanI, rstdI, Yq, b0);
    k_dw_t<<<dim3(128, 4, GB), blk, 0, stream>>>(Yq, vdw1, vdb1, Vt);
    k_av_mfma<<<dim3(128, GB), blk, 0, stream>>>(Sbf, Vt, A2);

    // ---- fused final linear + residual (single out write) ----
    k_final2_mfma<<<dim3(128, GB), blk, 0, stream>>>(A1, A2, lwbf, lb, F_i, F_w, out, b0);
  }
}

// Round 7
// 793.131 us; speedup vs baseline: 1.1059x; 1.0043x over previous
//
#include <hip/hip_runtime.h>
#include <cstddef>
#include <cstring>

#define HW 16384
#define CC 128
#define NB 8
#define GB 4   // batches per group

typedef short bf16x8_t __attribute__((ext_vector_type(8)));
typedef float floatx4 __attribute__((ext_vector_type(4)));

__device__ inline unsigned short f2bf(float f) {
  unsigned u; __builtin_memcpy(&u, &f, 4);
  u += 0x7fffu + ((u >> 16) & 1u);
  return (unsigned short)(u >> 16);
}
__device__ inline float bf2f(unsigned short s) {
  unsigned u = ((unsigned)s) << 16; float f; __builtin_memcpy(&f, &u, 4);
  return f;
}

// ---------------- one-time weight prep: (W*g) -> hi/lo bf16; lw -> bf16 -----
__global__ __launch_bounds__(256) void k_prep_w(
    const float* __restrict__ qw1, const float* __restrict__ kw1,
    const float* __restrict__ vw1, const float* __restrict__ qw2,
    const float* __restrict__ kw2, const float* __restrict__ vw2,
    const float* __restrict__ g1, const float* __restrict__ g2,
    const float* __restrict__ lw,
    unsigned short* __restrict__ Wsplit, unsigned short* __restrict__ lwbf) {
  const int t = threadIdx.x;
  const int m = blockIdx.y;
  if (m < 6) {
    const float* W = (m == 0) ? qw1 : (m == 1) ? kw1 : (m == 2) ? vw1
                   : (m == 3) ? qw2 : (m == 4) ? kw2 : vw2;
    const float* g = (m < 3) ? g1 : g2;
    const int idx = blockIdx.x * 256 + t;     // 0..2047
    const int o = idx >> 4;
    const int c0 = (idx & 15) * 8;
    unsigned short* hi = Wsplit + m * 32768 + o * 128 + c0;
    unsigned short* lo = hi + 16384;
#pragma unroll
    for (int j = 0; j < 8; ++j) {
      float v = W[o * 128 + c0 + j] * g[c0 + j];
      unsigned short h = f2bf(v);
      hi[j] = h;
      lo[j] = f2bf(v - bf2f(h));
    }
  } else {
    const int idx = blockIdx.x * 256 + t;     // 0..2047 (x16 elems = 32768)
#pragma unroll
    for (int j = 0; j < 16; ++j)
      lwbf[idx * 16 + j] = f2bf(lw[idx * 16 + j]);
  }
}

// ---------------- LN stats stage 1: split-c partial sums --------------------
// grid (256 p-blocks, 4 c-chunks, 2 inputs) = 2048 blocks (8/CU).
// Each thread sums 32 channels for 2 pixels. Partials -> Part (in P region).
// Part layout per (which,chunk): [131072] s then [131072] ss.
__global__ __launch_bounds__(256) void k_ln_part(
    const float* __restrict__ xi, const float* __restrict__ xw,
    float* __restrict__ Part) {
  const int which = blockIdx.z;
  const int chunk = blockIdx.y;
  const float* x = which ? xw : xi;
  int idx = blockIdx.x * 256 + threadIdx.x;   // 0 .. 65535
  int p2 = idx * 2;
  int b = p2 >> 14;
  int p = p2 & (HW - 1);
  const float* xp = x + ((size_t)b << 21) + ((size_t)(chunk * 32) << 14) + p;
  float s0 = 0.f, ss0 = 0.f, s1 = 0.f, ss1 = 0.f;
#pragma unroll 4
  for (int c = 0; c < 32; ++c) {
    float2 v = *reinterpret_cast<const float2*>(xp + ((size_t)c << 14));
    s0 += v.x; ss0 += v.x * v.x;
    s1 += v.y; ss1 += v.y * v.y;
  }
  float* base = Part + ((size_t)(which * 4 + chunk)) * 262144;
  *reinterpret_cast<float2*>(base + p2) = (float2){s0, s1};
  *reinterpret_cast<float2*>(base + 131072 + p2) = (float2){ss0, ss1};
}

// ---------------- LN stats stage 2: combine 4 chunks, mean/rstd -------------
__global__ __launch_bounds__(256) void k_ln_fin(
    const float* __restrict__ Part,
    float* __restrict__ meanI, float* __restrict__ rstdI,
    float* __restrict__ meanW, float* __restrict__ rstdW) {
  const int which = blockIdx.y;
  int idx = blockIdx.x * 256 + threadIdx.x;   // 0 .. 131071
  const float* base = Part + ((size_t)which * 4) * 262144;
  float s = 0.f, ss = 0.f;
#pragma unroll
  for (int ch = 0; ch < 4; ++ch) {
    s += base[(size_t)ch * 262144 + idx];
    ss += base[(size_t)ch * 262144 + 131072 + idx];
  }
  float m = s * (1.0f / CC);
  float var = ss * (1.0f / CC) - m * m;
  float* mean = which ? meanW : meanI;
  float* rstd = which ? rstdW : rstdI;
  mean[idx] = m;
  rstd[idx] = rsqrtf(var + 1e-5f);
}

// ---------------- conv1x1 per-block body (round-2 proven, 128-wide) --------
__device__ __forceinline__ void conv_body(
    const float* __restrict__ X,
    const unsigned short* __restrict__ Whi, const unsigned short* __restrict__ Wlo,
    const float* __restrict__ bias,
    const float* __restrict__ mean, const float* __restrict__ rstd,
    float* __restrict__ Y, int b0, int bl, int p0,
    float (*raw)[132], short (*Bh)[40], short (*Bl)[40]) {
  const int b = b0 + bl;
  const int t = threadIdx.x;
  const int lane = t & 63, wv = t >> 6;
  const int quad = lane >> 4, l15 = lane & 15;
  const int wr = wv >> 1, wc = wv & 1;

  const int s1c = t >> 3, s1p = (t & 7) * 16;
  const int s2p = t & 127, s2o = t >> 7;
  const float mu = mean[b * HW + p0 + s2p];
  const float rs = rstd[b * HW + p0 + s2p];

  const float* Xb = X + ((size_t)b << 21);
  floatx4 acc[4][4];
#pragma unroll
  for (int i = 0; i < 4; ++i)
#pragma unroll
    for (int j = 0; j < 4; ++j) acc[i][j] = (floatx4){0.f, 0.f, 0.f, 0.f};

  for (int k0 = 0; k0 < 128; k0 += 32) {
    {
      const float* xp = Xb + ((size_t)(k0 + s1c) << 14) + p0 + s1p;
#pragma unroll
      for (int u = 0; u < 4; ++u)
        *reinterpret_cast<float4*>(&raw[s1c][s1p + 4 * u]) =
            *reinterpret_cast<const float4*>(xp + 4 * u);
    }
    __syncthreads();
#pragma unroll
    for (int item = 0; item < 2; ++item) {
      const int oct = s2o + 2 * item;     // 0..3
      short th[8], tl[8];
#pragma unroll
      for (int jj = 0; jj < 8; ++jj) {
        float v = (raw[oct * 8 + jj][s2p] - mu) * rs;
        unsigned short h = f2bf(v);
        th[jj] = (short)h;
        tl[jj] = (short)f2bf(v - bf2f(h));
      }
      *reinterpret_cast<bf16x8_t*>(&Bh[s2p][oct * 8]) =
          *reinterpret_cast<bf16x8_t*>(&th[0]);
      *reinterpret_cast<bf16x8_t*>(&Bl[s2p][oct * 8]) =
          *reinterpret_cast<bf16x8_t*>(&tl[0]);
    }
    __syncthreads();
    bf16x8_t afh[4], afl[4], bfh[4], bfl[4];
#pragma unroll
    for (int i = 0; i < 4; ++i) {
      const int m = wr * 64 + i * 16 + l15;
      afh[i] = *reinterpret_cast<const bf16x8_t*>(Whi + m * 128 + k0 + quad * 8);
      afl[i] = *reinterpret_cast<const bf16x8_t*>(Wlo + m * 128 + k0 + quad * 8);
    }
#pragma unroll
    for (int j = 0; j < 4; ++j) {
      const int p = wc * 64 + j * 16 + l15;
      bfh[j] = *reinterpret_cast<const bf16x8_t*>(&Bh[p][quad * 8]);
      bfl[j] = *reinterpret_cast<const bf16x8_t*>(&Bl[p][quad * 8]);
    }
#pragma unroll
    for (int i = 0; i < 4; ++i)
#pragma unroll
      for (int j = 0; j < 4; ++j) {
        acc[i][j] = __builtin_amdgcn_mfma_f32_16x16x32_bf16(afh[i], bfh[j], acc[i][j], 0, 0, 0);
        acc[i][j] = __builtin_amdgcn_mfma_f32_16x16x32_bf16(afh[i], bfl[j], acc[i][j], 0, 0, 0);
        acc[i][j] = __builtin_amdgcn_mfma_f32_16x16x32_bf16(afl[i], bfh[j], acc[i][j], 0, 0, 0);
      }
    __syncthreads();
  }
  float* Yb = Y + ((size_t)bl << 21);
#pragma unroll
  for (int i = 0; i < 4; ++i) {
#pragma unroll
    for (int j = 0; j < 4; ++j) {
#pragma unroll
      for (int r = 0; r < 4; ++r) {
        const int o = wr * 64 + i * 16 + quad * 4 + r;
        const int p = p0 + wc * 64 + j * 16 + l15;
        Yb[((size_t)o << 14) + p] = acc[i][j][r] + bias[o];
      }
    }
  }
}

// single conv (V path)
__global__ __launch_bounds__(256) void k_conv1x1_mfma(
    const float* __restrict__ X,
    const unsigned short* __restrict__ Whi, const unsigned short* __restrict__ Wlo,
    const float* __restrict__ bias,
    const float* __restrict__ mean, const float* __restrict__ rstd,
    float* __restrict__ Y, int b0) {
  __shared__ __align__(16) float raw[32][132];
  __shared__ __align__(16) short Bh[128][40];
  __shared__ __align__(16) short Bl[128][40];
  conv_body(X, Whi, Wlo, bias, mean, rstd, Y, b0,
            blockIdx.y, blockIdx.x * 128, raw, Bh, Bl);
}

// fused Q+K convs: blockIdx.z selects the parameter set.
__global__ __launch_bounds__(256) void k_convQK_mfma(
    const float* __restrict__ Xq,
    const unsigned short* __restrict__ Wqhi, const unsigned short* __restrict__ Wqlo,
    const float* __restrict__ qbias,
    const float* __restrict__ meanq, const float* __restrict__ rstdq,
    float* __restrict__ Yq,
    const float* __restrict__ Xk,
    const unsigned short* __restrict__ Wkhi, const unsigned short* __restrict__ Wklo,
    const float* __restrict__ kbias,
    const float* __restrict__ meank, const float* __restrict__ rstdk,
    float* __restrict__ Yk, int b0) {
  __shared__ __align__(16) float raw[32][132];
  __shared__ __align__(16) short Bh[128][40];
  __shared__ __align__(16) short Bl[128][40];
  const int z = blockIdx.z;
  conv_body(z ? Xk : Xq, z ? Wkhi : Wqhi, z ? Wklo : Wqlo,
            z ? kbias : qbias, z ? meank : meanq, z ? rstdk : rstdq,
            z ? Yk : Yq, b0, blockIdx.y, blockIdx.x * 128, raw, Bh, Bl);
}

// ---------------- split-bf16 MFMA score GEMM with fused depthwise 3x3 --------
__global__ __launch_bounds__(256) void k_score_mfma(
    const float* __restrict__ Yq, const float* __restrict__ Yk,
    const float* __restrict__ qdw, const float* __restrict__ qdb,
    const float* __restrict__ kdw, const float* __restrict__ kdb,
    float* __restrict__ P) {
  __shared__ __align__(16) float raw[32][132];   // dw out chunk [h][w]
  __shared__ __align__(16) short Ah[128][40];    // Q side [w][h] hi
  __shared__ __align__(16) short Al[128][40];
  __shared__ __align__(16) short Bh[128][40];    // K side [w][h] hi
  __shared__ __align__(16) short Bl[128][40];
  const int ch = blockIdx.x;
  const int bl = blockIdx.y;
  const int t = threadIdx.x;
  const int lane = t & 63, wv = t >> 6;
  const int quad = lane >> 4, l15 = lane & 15;
  const int wr = wv >> 1, wc = wv & 1;
  const int h_loc = t >> 3;
  const int w0 = (t & 7) * 16;
  const int s2w = t & 127, s2o = t >> 7;
  const int cc = ch;
  const float* Yqb = Yq + ((size_t)bl << 21) + ((size_t)cc << 14);
  const float* Ykb = Yk + ((size_t)bl << 21) + ((size_t)cc << 14);
  const float* qwt = qdw + cc * 9;
  const float* kwt = kdw + cc * 9;
  const float qbv = qdb[cc], kbv = kdb[cc];

  floatx4 acc[4][4];
#pragma unroll
  for (int i = 0; i < 4; ++i)
#pragma unroll
    for (int j = 0; j < 4; ++j) acc[i][j] = (floatx4){0.f, 0.f, 0.f, 0.f};

  for (int k0 = 0; k0 < 128; k0 += 32) {
    const int h = k0 + h_loc;
#pragma unroll
    for (int side = 0; side < 2; ++side) {
      // ---- fused dw 3x3: 16 contiguous w at view-row h ----
      const float* Yc = side ? Ykb : Yqb;
      const float* wt = side ? kwt : qwt;
      const float bias = side ? kbv : qbv;
      float a[16];
#pragma unroll
      for (int j = 0; j < 16; ++j) a[j] = bias;
#pragma unroll
      for (int dy = 0; dy < 3; ++dy) {
        const int hh = h + dy - 1;
        if (hh < 0 || hh > 127) continue;
        const float* rp = Yc + (hh << 7) + w0;
        float4 f0 = *reinterpret_cast<const float4*>(rp);
        float4 f1 = *reinterpret_cast<const float4*>(rp + 4);
        float4 f2 = *reinterpret_cast<const float4*>(rp + 8);
        float4 f3 = *reinterpret_cast<const float4*>(rp + 12);
        float s[18];
        s[1] = f0.x;  s[2] = f0.y;  s[3] = f0.z;  s[4] = f0.w;
        s[5] = f1.x;  s[6] = f1.y;  s[7] = f1.z;  s[8] = f1.w;
        s[9] = f2.x;  s[10] = f2.y; s[11] = f2.z; s[12] = f2.w;
        s[13] = f3.x; s[14] = f3.y; s[15] = f3.z; s[16] = f3.w;
        s[0] = (w0 > 0) ? rp[-1] : 0.f;
        s[17] = (w0 < 112) ? rp[16] : 0.f;
        const float wa = wt[dy * 3 + 0], wb = wt[dy * 3 + 1], wc2 = wt[dy * 3 + 2];
#pragma unroll
        for (int j = 0; j < 16; ++j)
          a[j] = fmaf(s[j], wa, fmaf(s[j + 1], wb, fmaf(s[j + 2], wc2, a[j])));
      }
#pragma unroll
      for (int u = 0; u < 4; ++u)
        *reinterpret_cast<float4*>(&raw[h_loc][w0 + 4 * u]) =
            (float4){a[4 * u], a[4 * u + 1], a[4 * u + 2], a[4 * u + 3]};
      __syncthreads();
      // ---- transpose [h][w] -> [w][h] + hi/lo split ----
      short* dh = side ? &Bh[0][0] : &Ah[0][0];
      short* dl = side ? &Bl[0][0] : &Al[0][0];
#pragma unroll
      for (int item = 0; item < 2; ++item) {
        const int oct = s2o + 2 * item;   // 0..3
        short th[8], tl[8];
#pragma unroll
        for (int jj = 0; jj < 8; ++jj) {
          float v = raw[oct * 8 + jj][s2w];
          unsigned short hb = f2bf(v);
          th[jj] = (short)hb;
          tl[jj] = (short)f2bf(v - bf2f(hb));
        }
        *reinterpret_cast<bf16x8_t*>(&dh[s2w * 40 + oct * 8]) =
            *reinterpret_cast<bf16x8_t*>(&th[0]);
        *reinterpret_cast<bf16x8_t*>(&dl[s2w * 40 + oct * 8]) =
            *reinterpret_cast<bf16x8_t*>(&tl[0]);
      }
      __syncthreads();
    }
    // ---- MFMA, 3 split passes ----
    bf16x8_t afh[4], afl[4], bfh[4], bfl[4];
#pragma unroll
    for (int i = 0; i < 4; ++i) {
      const int m = wr * 64 + i * 16 + l15;
      afh[i] = *reinterpret_cast<const bf16x8_t*>(&Ah[m][quad * 8]);
      afl[i] = *reinterpret_cast<const bf16x8_t*>(&Al[m][quad * 8]);
    }
#pragma unroll
    for (int j = 0; j < 4; ++j) {
      const int n = wc * 64 + j * 16 + l15;
      bfh[j] = *reinterpret_cast<const bf16x8_t*>(&Bh[n][quad * 8]);
      bfl[j] = *reinterpret_cast<const bf16x8_t*>(&Bl[n][quad * 8]);
    }
#pragma unroll
    for (int i = 0; i < 4; ++i)
#pragma unroll
      for (int j = 0; j < 4; ++j) {
        acc[i][j] = __builtin_amdgcn_mfma_f32_16x16x32_bf16(afh[i], bfh[j], acc[i][j], 0, 0, 0);
        acc[i][j] = __builtin_amdgcn_mfma_f32_16x16x32_bf16(afh[i], bfl[j], acc[i][j], 0, 0, 0);
        acc[i][j] = __builtin_amdgcn_mfma_f32_16x16x32_bf16(afl[i], bfh[j], acc[i][j], 0, 0, 0);
      }
  }
  float* Pp = P + ((size_t)(ch * GB + bl) << 14);
#pragma unroll
  for (int i = 0; i < 4; ++i) {
#pragma unroll
    for (int j = 0; j < 4; ++j) {
#pragma unroll
      for (int r = 0; r < 4; ++r) {
        const int c = wr * 64 + i * 16 + quad * 4 + r;
        const int d = wc * 64 + j * 16 + l15;
        Pp[c * 128 + d] = acc[i][j][r];
      }
    }
  }
}

// ---------------- fused: split-K reduce + softmax -> bf16 -------------------
// 4-way in-block ch-split: 256 threads, group g = t>>6 sums 32 channels for
// a float2 d-pair; LDS combine in ascending-g order, softmax on lanes < 128.
__global__ __launch_bounds__(256) void k_reduce_softmax(
    const float* __restrict__ P, unsigned short* __restrict__ Sbf) {
  __shared__ float part[4][128];
  __shared__ float red[128];
  const int row = blockIdx.x;            // bl*128 + c
  const int bl = row >> 7, c = row & 127;
  const int t = threadIdx.x;
  const int g = t >> 6;                  // ch group 0..3
  const int dl = (t & 63) * 2;           // d pair
  float p0 = 0.f, p1 = 0.f;
#pragma unroll 4
  for (int cq = 0; cq < 32; ++cq) {
    const int ch = g * 32 + cq;
    float2 v = *reinterpret_cast<const float2*>(
        P + ((size_t)(ch * GB + bl) << 14) + ((size_t)c << 7) + dl);
    p0 += v.x;
    p1 += v.y;
  }
  part[g][dl] = p0;
  part[g][dl + 1] = p1;
  __syncthreads();
  float v = 0.f, e = 0.f;
  if (t < 128) {
    v = part[0][t] + part[1][t] + part[2][t] + part[3][t];
    red[t] = v;
  }
  __syncthreads();
  for (int s = 64; s > 0; s >>= 1) {
    if (t < s) red[t] = fmaxf(red[t], red[t + s]);
    __syncthreads();
  }
  float mx = red[0];
  __syncthreads();
  if (t < 128) {
    e = expf(v - mx);
    red[t] = e;
  }
  __syncthreads();
  for (int s = 64; s > 0; s >>= 1) {
    if (t < s) red[t] += red[t + s];
    __syncthreads();
  }
  if (t < 128)
    Sbf[((size_t)bl << 14) + ((size_t)c << 7) + t] = f2bf(e / red[0]);
}

// ---------------- depthwise 3x3 + transpose: Vt[p][c] bf16 -----------------
__global__ __launch_bounds__(256) void k_dw_t(const float* __restrict__ Y,
                                              const float* __restrict__ Kw,
                                              const float* __restrict__ db,
                                              unsigned short* __restrict__ Vt) {
  __shared__ unsigned short T[128][33];
  const int h = blockIdx.x;
  const int c0 = blockIdx.y * 32;
  const int bl = blockIdx.z;
  const int t = threadIdx.x;
  const int cl = t >> 3;
  const int w0 = (t & 7) * 16;
  const int c = c0 + cl;
  const float* Yc = Y + ((size_t)bl << 21) + ((size_t)c << 14);
  const float* wt = Kw + c * 9;
  float a[16];
#pragma unroll
  for (int j = 0; j < 16; ++j) a[j] = db[c];
#pragma unroll
  for (int dy = 0; dy < 3; ++dy) {
    const int hh = h + dy - 1;
    if (hh < 0 || hh > 127) continue;
    const float* rp = Yc + (hh << 7) + w0;
    float4 f0 = *reinterpret_cast<const float4*>(rp);
    float4 f1 = *reinterpret_cast<const float4*>(rp + 4);
    float4 f2 = *reinterpret_cast<const float4*>(rp + 8);
    float4 f3 = *reinterpret_cast<const float4*>(rp + 12);
    float s[18];
    s[1] = f0.x;  s[2] = f0.y;  s[3] = f0.z;  s[4] = f0.w;
    s[5] = f1.x;  s[6] = f1.y;  s[7] = f1.z;  s[8] = f1.w;
    s[9] = f2.x;  s[10] = f2.y; s[11] = f2.z; s[12] = f2.w;
    s[13] = f3.x; s[14] = f3.y; s[15] = f3.z; s[16] = f3.w;
    s[0] = (w0 > 0) ? rp[-1] : 0.f;
    s[17] = (w0 < 112) ? rp[16] : 0.f;
    const float wa = wt[dy * 3 + 0], wb = wt[dy * 3 + 1], wc2 = wt[dy * 3 + 2];
#pragma unroll
    for (int j = 0; j < 16; ++j)
      a[j] = fmaf(s[j], wa, fmaf(s[j + 1], wb, fmaf(s[j + 2], wc2, a[j])));
  }
#pragma unroll
  for (int j = 0; j < 16; ++j) T[w0 + j][cl] = f2bf(a[j]);
  __syncthreads();
  const int w = t >> 1, half = t & 1;
  unsigned short tmp[16];
#pragma unroll
  for (int j = 0; j < 16; ++j) tmp[j] = T[w][half * 16 + j];
  uint4 v0, v1;
  unsigned* vp0 = reinterpret_cast<unsigned*>(&v0);
  unsigned* vp1 = reinterpret_cast<unsigned*>(&v1);
#pragma unroll
  for (int j = 0; j < 4; ++j) {
    vp0[j] = (unsigned)tmp[2 * j] | ((unsigned)tmp[2 * j + 1] << 16);
    vp1[j] = (unsigned)tmp[8 + 2 * j] | ((unsigned)tmp[8 + 2 * j + 1] << 16);
  }
  unsigned short* dst = Vt + ((size_t)bl << 21) + ((size_t)((h << 7) + w) << 7)
                        + c0 + half * 16;
  *reinterpret_cast<uint4*>(dst) = v0;
  *reinterpret_cast<uint4*>(dst + 8) = v1;
}

// ---------------- MFMA: O[c,p] = sum_d Att[c,d] * V[d,p] — LDS-free --------
__global__ __launch_bounds__(256) void k_av_mfma(
    const unsigned short* __restrict__ Sbf, const unsigned short* __restrict__ Vt,
    unsigned short* __restrict__ O) {
  const int bl = blockIdx.y;
  const int p0 = blockIdx.x * 128;
  const int t = threadIdx.x;
  const int lane = t & 63, wv = t >> 6;
  const int quad = lane >> 4, l15 = lane & 15;
  const int wr = wv >> 1, wc = wv & 1;
  const unsigned short* Sb = Sbf + ((size_t)bl << 14);
  floatx4 acc[4][4];
#pragma unroll
  for (int i = 0; i < 4; ++i)
#pragma unroll
    for (int j = 0; j < 4; ++j) acc[i][j] = (floatx4){0.f, 0.f, 0.f, 0.f};
  const unsigned short* Vb = Vt + ((size_t)bl << 21);
#pragma unroll
  for (int d0 = 0; d0 < 128; d0 += 32) {
    bf16x8_t af[4], bf[4];
#pragma unroll
    for (int i = 0; i < 4; ++i) {
      const int m = wr * 64 + i * 16 + l15;
      af[i] = *reinterpret_cast<const bf16x8_t*>(Sb + m * 128 + d0 + quad * 8);
    }
#pragma unroll
    for (int j = 0; j < 4; ++j) {
      const int p = p0 + wc * 64 + j * 16 + l15;
      bf[j] = *reinterpret_cast<const bf16x8_t*>(Vb + ((size_t)p << 7) + d0 + quad * 8);
    }
#pragma unroll
    for (int i = 0; i < 4; ++i)
#pragma unroll
      for (int j = 0; j < 4; ++j)
        acc[i][j] = __builtin_amdgcn_mfma_f32_16x16x32_bf16(af[i], bf[j], acc[i][j], 0, 0, 0);
  }
  unsigned short* Ob = O + ((size_t)bl << 21);
#pragma unroll
  for (int i = 0; i < 4; ++i) {
#pragma unroll
    for (int j = 0; j < 4; ++j) {
#pragma unroll
      for (int r = 0; r < 4; ++r) {
        const int c = wr * 64 + i * 16 + quad * 4 + r;
        const int p = p0 + wc * 64 + j * 16 + l15;
        Ob[((size_t)c << 14) + p] = f2bf(acc[i][j][r]);
      }
    }
  }
}

// ---------------- MFMA final: LDS-free, lw pre-converted to bf16 ------------
__global__ __launch_bounds__(256) void k_final2_mfma(
    const unsigned short* __restrict__ A1, const unsigned short* __restrict__ A2,
    const unsigned short* __restrict__ lwbf, const float* __restrict__ lb,
    const float* __restrict__ Fi, const float* __restrict__ Fw,
    float* __restrict__ out, int b0) {
  const int c2 = blockIdx.x;
  const int bl = blockIdx.y;
  const int b = b0 + bl;
  const int t = threadIdx.x;
  const int lane = t & 63, wv = t >> 6;
  const int quad = lane >> 4, l15 = lane & 15;
  const int wr = wv >> 1, wc = wv & 1;
  floatx4 acc[4][4];
#pragma unroll
  for (int i = 0; i < 4; ++i)
#pragma unroll
    for (int j = 0; j < 4; ++j) acc[i][j] = (floatx4){0.f, 0.f, 0.f, 0.f};
#pragma unroll
  for (int phase = 0; phase < 2; ++phase) {
    const unsigned short* Ub = (phase ? A2 : A1) + ((size_t)bl << 21) + c2 * 128;
#pragma unroll
    for (int d0 = 0; d0 < 128; d0 += 32) {
      bf16x8_t af[4], bf[4];
#pragma unroll
      for (int i = 0; i < 4; ++i) {
        const int m = wr * 64 + i * 16 + l15;
        af[i] = *reinterpret_cast<const bf16x8_t*>(
            lwbf + m * 256 + phase * 128 + d0 + quad * 8);
      }
#pragma unroll
      for (int j = 0; j < 4; ++j) {
        const int n = wc * 64 + j * 16 + l15;
        bf[j] = *reinterpret_cast<const bf16x8_t*>(Ub + ((size_t)n << 14) + d0 + quad * 8);
      }
#pragma unroll
      for (int i = 0; i < 4; ++i)
#pragma unroll
        for (int j = 0; j < 4; ++j)
          acc[i][j] = __builtin_amdgcn_mfma_f32_16x16x32_bf16(af[i], bf[j], acc[i][j], 0, 0, 0);
    }
  }
  const size_t obase = ((size_t)b << 21) + ((size_t)c2 << 14);
#pragma unroll
  for (int i = 0; i < 4; ++i) {
#pragma unroll
    for (int j = 0; j < 4; ++j) {
#pragma unroll
      for (int r = 0; r < 4; ++r) {
        const int h2 = wr * 64 + i * 16 + quad * 4 + r;
        const int w2 = wc * 64 + j * 16 + l15;
        const size_t a = obase + ((size_t)h2 << 7) + w2;
        out[a] = acc[i][j][r] + lb[h2] + Fi[a] + Fw[a];
      }
    }
  }
}

extern "C" void kernel_launch(void* const* d_in, const int* in_sizes, int n_in,
                              void* d_out, int out_size, void* d_ws, size_t ws_size,
                              hipStream_t stream) {
  const float* F_i  = (const float*)d_in[0];
  const float* F_w  = (const float*)d_in[1];
  const float* g1   = (const float*)d_in[2];
  const float* g2   = (const float*)d_in[3];
  const float* qw1  = (const float*)d_in[4];
  const float* kw1  = (const float*)d_in[5];
  const float* vw1  = (const float*)d_in[6];
  const float* qw2  = (const float*)d_in[7];
  const float* kw2  = (const float*)d_in[8];
  const float* vw2  = (const float*)d_in[9];
  const float* qb1  = (const float*)d_in[10];
  const float* kb1  = (const float*)d_in[11];
  const float* vb1  = (const float*)d_in[12];
  const float* qb2  = (const float*)d_in[13];
  const float* kb2  = (const float*)d_in[14];
  const float* vb2  = (const float*)d_in[15];
  const float* qdw1 = (const float*)d_in[16];
  const float* kdw1 = (const float*)d_in[17];
  const float* vdw1 = (const float*)d_in[18];
  const float* qdw2 = (const float*)d_in[19];
  const float* kdw2 = (const float*)d_in[20];
  const float* vdw2 = (const float*)d_in[21];
  const float* qdb1 = (const float*)d_in[22];
  const float* kdb1 = (const float*)d_in[23];
  const float* vdb1 = (const float*)d_in[24];
  const float* qdb2 = (const float*)d_in[25];
  const float* kdb2 = (const float*)d_in[26];
  const float* vdb2 = (const float*)d_in[27];
  const float* lw   = (const float*)d_in[28];
  const float* lb   = (const float*)d_in[29];
  float* out = (float*)d_out;

  // ---- workspace (~114.6 MiB peak; <=116 MiB proven safe) ----
  char* w = (char*)d_ws;
  const size_t NTOT = (size_t)NB * HW;                      // 131072
  float* meanI = (float*)w; w += NTOT * 4;
  float* rstdI = (float*)w; w += NTOT * 4;
  float* meanW = (float*)w; w += NTOT * 4;
  float* rstdW = (float*)w; w += NTOT * 4;
  unsigned short* Sbf = (unsigned short*)w; w += (size_t)GB * HW * 2;     // 128 KiB
  unsigned short* Wsplit = (unsigned short*)w; w += 6 * 32768 * 2;        // 384 KiB
  unsigned short* lwbf = (unsigned short*)w; w += 32768 * 2;              // 64 KiB
  float* P     = (float*)w; w += (size_t)128 * GB * HW * 4; // 32 MiB
  float* Part  = P;   // 8 MiB LN partials overlay P (P unused until score)
  float* Yq    = (float*)w; w += ((size_t)GB << 21) * 4;    // 32 MiB
  char*  Ykreg = w;         w += ((size_t)GB << 21) * 4;    // 32 MiB (overlaid)
  float* Yk    = (float*)Ykreg;
  unsigned short* Vt = (unsigned short*)Ykreg;                            // 16 MiB
  unsigned short* A2 = (unsigned short*)(Ykreg + ((size_t)GB << 21) * 2); // 16 MiB
  unsigned short* A1 = (unsigned short*)w; w += ((size_t)GB << 21) * 2;   // 16 MiB

  // pre-split conv weights (W*g -> hi/lo bf16) and lw -> bf16
  const unsigned short* Wh0 = Wsplit + 0 * 32768;  // qw1*g1
  const unsigned short* Wh1 = Wsplit + 1 * 32768;  // kw1*g1
  const unsigned short* Wh2 = Wsplit + 2 * 32768;  // vw1*g1
  const unsigned short* Wh3 = Wsplit + 3 * 32768;  // qw2*g2
  const unsigned short* Wh4 = Wsplit + 4 * 32768;  // kw2*g2
  const unsigned short* Wh5 = Wsplit + 5 * 32768;  // vw2*g2

  dim3 blk(256);
  k_prep_w<<<dim3(8, 7), blk, 0, stream>>>(qw1, kw1, vw1, qw2, kw2, vw2,
                                           g1, g2, lw, Wsplit, lwbf);
  k_ln_part<<<dim3(256, 4, 2), blk, 0, stream>>>(F_i, F_w, Part);
  k_ln_fin<<<dim3(512, 2), blk, 0, stream>>>(Part, meanI, rstdI, meanW, rstdW);

  for (int b0 = 0; b0 < NB; b0 += GB) {
    // ---- attention 1: a1 = softmax(Qi^T Kw) ; Aw = a1 @ Vw -> A1 ----
    k_convQK_mfma<<<dim3(128, GB, 2), blk, 0, stream>>>(
        F_i, Wh0, Wh0 + 16384, qb1, meanI, rstdI, Yq,
        F_w, Wh4, Wh4 + 16384, kb2, meanW, rstdW, Yk, b0);
    k_score_mfma<<<dim3(128, GB), blk, 0, stream>>>(Yq, Yk, qdw1, qdb1, kdw2, kdb2, P);
    k_reduce_softmax<<<dim3(GB * 128), blk, 0, stream>>>(P, Sbf);
    k_conv1x1_mfma<<<dim3(128, GB), blk, 0, stream>>>(F_w, Wh5, Wh5 + 16384, vb2, meanW, rstdW, Yq, b0);
    k_dw_t<<<dim3(128, 4, GB), blk, 0, stream>>>(Yq, vdw2, vdb2, Vt);
    k_av_mfma<<<dim3(128, GB), blk, 0, stream>>>(Sbf, Vt, A1);

    // ---- attention 2: a2 = softmax(Qw^T Ki) ; Ai = a2 @ Vi -> A2 ----
    k_convQK_mfma<<<dim3(128, GB, 2), blk, 0, stream>>>(
        F_w, Wh3, Wh3 + 16384, qb2, meanW, rstdW, Yq,
        F_i, Wh1, Wh1 + 16384, kb1, meanI, rstdI, Yk, b0);
    k_score_mfma<<<dim3(128, GB), blk, 0, stream>>>(Yq, Yk, qdw2, qdb2, kdw1, kdb1, P);
    k_reduce_softmax<<<dim3(GB * 128), blk, 0, stream>>>(P, Sbf);
    k_conv1x1_mfma<<<dim3(128, GB), blk, 0, stream>>>(F_i, Wh2, Wh2 + 16384, vb1, meanI, rstdI, Yq, b0);
    k_dw_t<<<dim3(128, 4, GB), blk, 0, stream>>>(Yq, vdw1, vdb1, Vt);
    k_av_mfma<<<dim3(128, GB), blk, 0, stream>>>(Sbf, Vt, A2);

    // ---- fused final linear + residual (single out write) ----
    k_final2_mfma<<<dim3(128, GB), blk, 0, stream>>>(A1, A2, lwbf, lb, F_i, F_w, out, b0);
  }
}